// Round 1
// baseline (17461.462 us; speedup 1.0000x reference)
//
#include <hip/hip_runtime.h>
#include <math.h>

#define TT 1024
#define BB 2
#define DD 768
#define HH 12
#define NHD 64
#define LL 12
#define VV 50257
#define MROWS (BB*TT)

// ---------------- embedding ----------------
__global__ void embed_kernel(const int* __restrict__ idx, const float* __restrict__ wte,
                             const float* __restrict__ wpe, float* __restrict__ x) {
    int m = blockIdx.x;            // 0..2047 (= b*T + t)
    int t = m % TT;
    int tok = idx[m];
    const float* wrow = wte + (size_t)tok * DD;
    const float* prow = wpe + (size_t)t * DD;
    float* xrow = x + (size_t)m * DD;
    for (int c = threadIdx.x; c < DD; c += blockDim.x)
        xrow[c] = wrow[c] + prow[c];
}

// ---------------- layernorm (one block per row, D=768) ----------------
__global__ void ln_kernel(const float* __restrict__ x, const float* __restrict__ w,
                          const float* __restrict__ b, float* __restrict__ out) {
    __shared__ float red[256];
    int m = blockIdx.x;
    int tid = threadIdx.x;
    const float* xr = x + (size_t)m * DD;
    float v0 = xr[tid], v1 = xr[tid + 256], v2 = xr[tid + 512];
    red[tid] = v0 + v1 + v2;
    __syncthreads();
    for (int s = 128; s > 0; s >>= 1) { if (tid < s) red[tid] += red[tid + s]; __syncthreads(); }
    float mu = red[0] * (1.0f / DD);
    __syncthreads();
    float d0 = v0 - mu, d1 = v1 - mu, d2 = v2 - mu;
    red[tid] = d0 * d0 + d1 * d1 + d2 * d2;
    __syncthreads();
    for (int s = 128; s > 0; s >>= 1) { if (tid < s) red[tid] += red[tid + s]; __syncthreads(); }
    float rstd = rsqrtf(red[0] * (1.0f / DD) + 1e-5f);
    float* orow = out + (size_t)m * DD;
    orow[tid]       = d0 * rstd * w[tid]       + b[tid];
    orow[tid + 256] = d1 * rstd * w[tid + 256] + b[tid + 256];
    orow[tid + 512] = d2 * rstd * w[tid + 512] + b[tid + 512];
}

// ---------------- causal attention, one block per (b,h,q-row) ----------------
__global__ void attn_kernel(const float* __restrict__ qkv, float* __restrict__ out) {
    __shared__ float qs[NHD];
    __shared__ float s[TT];
    __shared__ float red[256];
    __shared__ float osum[4][NHD];
    int bid = blockIdx.x;
    int t = bid % TT;
    int h = (bid / TT) % HH;
    int b = bid / (TT * HH);
    int m = b * TT + t;
    int tid = threadIdx.x;
    const float* qp = qkv + (size_t)m * (3 * DD) + h * NHD;
    if (tid < NHD) qs[tid] = qp[tid];
    __syncthreads();

    float lmax = -1e30f;
    for (int j = tid; j <= t; j += 256) {
        const float* kp = qkv + (size_t)(b * TT + j) * (3 * DD) + DD + h * NHD;
        float acc = 0.f;
        #pragma unroll
        for (int d = 0; d < NHD; ++d) acc += qs[d] * kp[d];
        acc *= 0.125f;   // 1/sqrt(64)
        s[j] = acc;
        lmax = fmaxf(lmax, acc);
    }
    red[tid] = lmax; __syncthreads();
    for (int st = 128; st > 0; st >>= 1) { if (tid < st) red[tid] = fmaxf(red[tid], red[tid + st]); __syncthreads(); }
    float mx = red[0];
    __syncthreads();
    float lsum = 0.f;
    for (int j = tid; j <= t; j += 256) {
        float e = expf(s[j] - mx);
        s[j] = e;
        lsum += e;
    }
    red[tid] = lsum; __syncthreads();
    for (int st = 128; st > 0; st >>= 1) { if (tid < st) red[tid] += red[tid + st]; __syncthreads(); }
    float inv = 1.f / red[0];

    int g = tid >> 6, d = tid & 63;
    float part = 0.f;
    for (int j = g; j <= t; j += 4) {
        part += s[j] * qkv[(size_t)(b * TT + j) * (3 * DD) + 2 * DD + h * NHD + d];
    }
    osum[g][d] = part;
    __syncthreads();
    if (g == 0) {
        float o = (osum[0][d] + osum[1][d] + osum[2][d] + osum[3][d]) * inv;
        out[(size_t)m * DD + h * NHD + d] = o;
    }
}

// ---------------- generic tiled fp32 GEMM: C = act(A@W + bias) (+res) ----------------
// A: [M,K] row-major. If !BT: W is [K,N] row-major. If BT: W is [N,K] row-major (B=W^T).
template<bool BT, bool HAS_BIAS, bool GELU_ACT, bool RES>
__global__ void gemm_kernel(const float* __restrict__ A, const float* __restrict__ W,
                            const float* __restrict__ bias, const float* __restrict__ res,
                            float* __restrict__ C, int M, int N, int K) {
    const int BM = 64, BN = 64, BK = 16;
    __shared__ __align__(16) float As[BK][BM];
    __shared__ __align__(16) float Bs[BK][BN];
    int tid = threadIdx.x;
    int tx = tid & 15, ty = tid >> 4;
    int m0 = blockIdx.y * BM, n0 = blockIdx.x * BN;
    float acc[4][4] = {};

    for (int k0 = 0; k0 < K; k0 += BK) {
        {   // A tile 64x16, store transposed As[k][m]
            int r = tid >> 2, c4 = (tid & 3) * 4;
            const float4 av = *reinterpret_cast<const float4*>(&A[(size_t)(m0 + r) * K + k0 + c4]);
            As[c4 + 0][r] = av.x; As[c4 + 1][r] = av.y; As[c4 + 2][r] = av.z; As[c4 + 3][r] = av.w;
        }
        if (!BT) {  // B tile 16x64 direct
            int r = tid >> 4, c4 = (tid & 15) * 4;
            if (n0 + BN <= N) {
                const float4 bv = *reinterpret_cast<const float4*>(&W[(size_t)(k0 + r) * N + n0 + c4]);
                *reinterpret_cast<float4*>(&Bs[r][c4]) = bv;
            } else {
                for (int i = 0; i < 4; ++i) {
                    int n = n0 + c4 + i;
                    Bs[r][c4 + i] = (n < N) ? W[(size_t)(k0 + r) * N + n] : 0.f;
                }
            }
        } else {    // B[k][n] = W[n][k], W row-major [N,K]
            int nn = tid >> 2, c4 = (tid & 3) * 4;
            int n = n0 + nn;
            float4 bv = make_float4(0.f, 0.f, 0.f, 0.f);
            if (n < N) bv = *reinterpret_cast<const float4*>(&W[(size_t)n * K + k0 + c4]);
            Bs[c4 + 0][nn] = bv.x; Bs[c4 + 1][nn] = bv.y; Bs[c4 + 2][nn] = bv.z; Bs[c4 + 3][nn] = bv.w;
        }
        __syncthreads();
        #pragma unroll
        for (int kk = 0; kk < BK; ++kk) {
            float4 a = *reinterpret_cast<const float4*>(&As[kk][ty * 4]);
            float4 bq = *reinterpret_cast<const float4*>(&Bs[kk][tx * 4]);
            float av[4] = {a.x, a.y, a.z, a.w};
            float bv[4] = {bq.x, bq.y, bq.z, bq.w};
            #pragma unroll
            for (int i = 0; i < 4; ++i)
                #pragma unroll
                for (int j = 0; j < 4; ++j)
                    acc[i][j] += av[i] * bv[j];
        }
        __syncthreads();
    }

    #pragma unroll
    for (int i = 0; i < 4; ++i) {
        int m = m0 + ty * 4 + i;
        #pragma unroll
        for (int j = 0; j < 4; ++j) {
            int n = n0 + tx * 4 + j;
            if (n < N) {
                float v = acc[i][j];
                if (HAS_BIAS) v += bias[n];
                if (GELU_ACT) {
                    float u = v;
                    v = 0.5f * u * (1.0f + tanhf(0.7978845608028654f * (u + 0.044715f * u * u * u)));
                }
                if (RES) v += res[(size_t)m * N + n];
                C[(size_t)m * N + n] = v;
            }
        }
    }
}

// ---------------- loss ----------------
__global__ void zero_kernel(float* p) { if (threadIdx.x == 0) p[0] = 0.f; }

__global__ void loss_kernel(const float* __restrict__ logits, const int* __restrict__ targets,
                            float* __restrict__ acc) {
    __shared__ float red[256];
    int m = blockIdx.x;
    int tid = threadIdx.x;
    const float* lr = logits + (size_t)m * VV;
    float lmax = -1e30f;
    for (int v = tid; v < VV; v += 256) lmax = fmaxf(lmax, lr[v]);
    red[tid] = lmax; __syncthreads();
    for (int s = 128; s > 0; s >>= 1) { if (tid < s) red[tid] = fmaxf(red[tid], red[tid + s]); __syncthreads(); }
    float mx = red[0];
    __syncthreads();
    float lsum = 0.f;
    for (int v = tid; v < VV; v += 256) lsum += expf(lr[v] - mx);
    red[tid] = lsum; __syncthreads();
    for (int s = 128; s > 0; s >>= 1) { if (tid < s) red[tid] += red[tid + s]; __syncthreads(); }
    if (tid == 0) {
        float lse = logf(red[0]) + mx;
        float nll = lse - lr[targets[m]];
        atomicAdd(acc, nll);
    }
}

__global__ void loss_final(const float* __restrict__ acc, float* __restrict__ out) {
    if (threadIdx.x == 0) out[0] = acc[0] * (1.0f / (float)MROWS);
}

// ---------------- launch ----------------
extern "C" void kernel_launch(void* const* d_in, const int* in_sizes, int n_in,
                              void* d_out, int out_size, void* d_ws, size_t ws_size,
                              hipStream_t stream) {
    const int*   idx     = (const int*)d_in[0];
    const int*   targets = (const int*)d_in[1];
    const float* wte     = (const float*)d_in[2];
    const float* wpe     = (const float*)d_in[3];
    const float* ln1_w   = (const float*)d_in[4];
    const float* ln1_b   = (const float*)d_in[5];
    const float* qkv_w   = (const float*)d_in[6];
    const float* qkv_b   = (const float*)d_in[7];
    const float* proj_w  = (const float*)d_in[8];
    const float* proj_b  = (const float*)d_in[9];
    const float* ln2_w   = (const float*)d_in[10];
    const float* ln2_b   = (const float*)d_in[11];
    const float* fc_w    = (const float*)d_in[12];
    const float* fc_b    = (const float*)d_in[13];
    const float* fc2_w   = (const float*)d_in[14];
    const float* fc2_b   = (const float*)d_in[15];
    const float* lnf_w   = (const float*)d_in[16];
    const float* lnf_b   = (const float*)d_in[17];

    float* logits = (float*)d_out;
    float* loss_out = logits + (size_t)MROWS * VV;

    float* ws = (float*)d_ws;
    float* x      = ws;
    float* h      = x + (size_t)MROWS * DD;
    float* qkvbuf = h + (size_t)MROWS * DD;
    float* attnb  = qkvbuf + (size_t)MROWS * 3 * DD;
    float* fcbuf  = attnb + (size_t)MROWS * DD;
    float* lacc   = fcbuf + (size_t)MROWS * 4 * DD;

    dim3 blk(256);

    embed_kernel<<<MROWS, blk, 0, stream>>>(idx, wte, wpe, x);

    for (int l = 0; l < LL; ++l) {
        const float* l1w = ln1_w + (size_t)l * DD;
        const float* l1b = ln1_b + (size_t)l * DD;
        const float* qw  = qkv_w + (size_t)l * DD * 3 * DD;
        const float* qb  = qkv_b + (size_t)l * 3 * DD;
        const float* pw  = proj_w + (size_t)l * DD * DD;
        const float* pb  = proj_b + (size_t)l * DD;
        const float* l2w = ln2_w + (size_t)l * DD;
        const float* l2b = ln2_b + (size_t)l * DD;
        const float* fw  = fc_w + (size_t)l * DD * 4 * DD;
        const float* fb  = fc_b + (size_t)l * 4 * DD;
        const float* f2w = fc2_w + (size_t)l * 4 * DD * DD;
        const float* f2b = fc2_b + (size_t)l * DD;

        ln_kernel<<<MROWS, blk, 0, stream>>>(x, l1w, l1b, h);

        gemm_kernel<false, true, false, false><<<dim3((3 * DD) / 64, MROWS / 64), blk, 0, stream>>>(
            h, qw, qb, nullptr, qkvbuf, MROWS, 3 * DD, DD);

        attn_kernel<<<BB * HH * TT, blk, 0, stream>>>(qkvbuf, attnb);

        gemm_kernel<false, true, false, true><<<dim3(DD / 64, MROWS / 64), blk, 0, stream>>>(
            attnb, pw, pb, x, x, MROWS, DD, DD);

        ln_kernel<<<MROWS, blk, 0, stream>>>(x, l2w, l2b, h);

        gemm_kernel<false, true, true, false><<<dim3((4 * DD) / 64, MROWS / 64), blk, 0, stream>>>(
            h, fw, fb, nullptr, fcbuf, MROWS, 4 * DD, DD);

        gemm_kernel<false, true, false, true><<<dim3(DD / 64, MROWS / 64), blk, 0, stream>>>(
            fcbuf, f2w, f2b, x, x, MROWS, DD, 4 * DD);
    }

    ln_kernel<<<MROWS, blk, 0, stream>>>(x, lnf_w, lnf_b, h);

    gemm_kernel<true, false, false, false><<<dim3((VV + 63) / 64, MROWS / 64), blk, 0, stream>>>(
        h, wte, nullptr, nullptr, logits, MROWS, VV, DD);

    zero_kernel<<<1, 64, 0, stream>>>(lacc);
    loss_kernel<<<MROWS, blk, 0, stream>>>(logits, targets, lacc);
    loss_final<<<1, 64, 0, stream>>>(lacc, loss_out);
}

// Round 2
// 4369.605 us; speedup vs baseline: 3.9961x; 3.9961x over previous
//
#include <hip/hip_runtime.h>
#include <hip/hip_bf16.h>
#include <math.h>

#define TT 1024
#define BB 2
#define DD 768
#define HH 12
#define NHD 64
#define LL 12
#define VV 50257
#define MROWS (BB*TT)
#define VPAD 50304   // 393*128, padded vocab for B-tile staging

typedef __attribute__((ext_vector_type(4))) float f32x4;
typedef __attribute__((ext_vector_type(8))) __bf16 bf16x8;
typedef __hip_bfloat16 bf16;

__device__ __forceinline__ void gload_lds16(const bf16* g, bf16* l) {
    __builtin_amdgcn_global_load_lds((const __attribute__((address_space(1))) void*)g,
                                     (__attribute__((address_space(3))) void*)l, 16, 0, 0);
}

// ---------------- embedding (fp32 residual stream) ----------------
__global__ void embed_kernel(const int* __restrict__ idx, const float* __restrict__ wte,
                             const float* __restrict__ wpe, float* __restrict__ x) {
    int m = blockIdx.x;
    int t = m % TT;
    int tok = idx[m];
    const float* wrow = wte + (size_t)tok * DD;
    const float* prow = wpe + (size_t)t * DD;
    float* xrow = x + (size_t)m * DD;
    for (int c = threadIdx.x; c < DD; c += blockDim.x)
        xrow[c] = wrow[c] + prow[c];
}

// ---------------- layernorm: fp32 in -> bf16 out ----------------
__global__ void ln_kernel(const float* __restrict__ x, const float* __restrict__ w,
                          const float* __restrict__ b, bf16* __restrict__ out) {
    __shared__ float red[256];
    int m = blockIdx.x;
    int tid = threadIdx.x;
    const float* xr = x + (size_t)m * DD;
    float v0 = xr[tid], v1 = xr[tid + 256], v2 = xr[tid + 512];
    red[tid] = v0 + v1 + v2;
    __syncthreads();
    for (int s = 128; s > 0; s >>= 1) { if (tid < s) red[tid] += red[tid + s]; __syncthreads(); }
    float mu = red[0] * (1.0f / DD);
    __syncthreads();
    float d0 = v0 - mu, d1 = v1 - mu, d2 = v2 - mu;
    red[tid] = d0 * d0 + d1 * d1 + d2 * d2;
    __syncthreads();
    for (int s = 128; s > 0; s >>= 1) { if (tid < s) red[tid] += red[tid + s]; __syncthreads(); }
    float rstd = rsqrtf(red[0] * (1.0f / DD) + 1e-5f);
    bf16* orow = out + (size_t)m * DD;
    orow[tid]       = __float2bfloat16(d0 * rstd * w[tid]       + b[tid]);
    orow[tid + 256] = __float2bfloat16(d1 * rstd * w[tid + 256] + b[tid + 256]);
    orow[tid + 512] = __float2bfloat16(d2 * rstd * w[tid + 512] + b[tid + 512]);
}

// ---------------- fp32 -> bf16 cast (wte) ----------------
__global__ void cast_kernel(const float* __restrict__ src, bf16* __restrict__ dst, int n4) {
    int stride = gridDim.x * blockDim.x;
    for (int i = blockIdx.x * blockDim.x + threadIdx.x; i < n4; i += stride) {
        float4 v = *(const float4*)(src + (size_t)i * 4);
        bf16* d = dst + (size_t)i * 4;
        d[0] = __float2bfloat16(v.x); d[1] = __float2bfloat16(v.y);
        d[2] = __float2bfloat16(v.z); d[3] = __float2bfloat16(v.w);
    }
}

// ---------------- W[K,N] fp32 -> Wt[N,K] bf16 (32x32 LDS tile) ----------------
__global__ void tcast_kernel(const float* __restrict__ W, bf16* __restrict__ Wt, int K, int N) {
    __shared__ float t[32][33];
    int n0 = blockIdx.x * 32, k0 = blockIdx.y * 32;
    int c = threadIdx.x & 31, g = threadIdx.x >> 5;   // g = 0..7
    #pragma unroll
    for (int i = 0; i < 4; ++i) {
        int k = g * 4 + i;
        t[k][c] = W[(size_t)(k0 + k) * N + n0 + c];
    }
    __syncthreads();
    #pragma unroll
    for (int i = 0; i < 4; ++i) {
        int n = g * 4 + i;
        Wt[(size_t)(n0 + n) * K + k0 + c] = __float2bfloat16(t[c][n]);
    }
}

// ---------------- MFMA GEMM: C[M,N] = A[M,K] @ Wt[N,K]^T (+bias, gelu, res) ----
// A, Wt bf16 row-major with K contiguous. 128x128 tile, BK=32, 4 waves (2x2 of 64x64).
template<bool BIAS, bool GELU_, bool RES, bool OUTBF16, bool NCHECK>
__global__ __launch_bounds__(256, 2) void mgemm(
        const bf16* __restrict__ A, const bf16* __restrict__ Bm,
        const float* __restrict__ bias, const float* __restrict__ res,
        float* __restrict__ Cf, bf16* __restrict__ Cb, int M, int N, int K) {
    __shared__ __align__(16) bf16 As[128 * 32];
    __shared__ __align__(16) bf16 Bs[128 * 32];
    const int tid = threadIdx.x, lane = tid & 63, wid = tid >> 6;
    const int m0 = blockIdx.x * 128, n0 = blockIdx.y * 128;
    const int wr = (wid >> 1) * 64, wc = (wid & 1) * 64;
    const int fr = lane & 15, fq = lane >> 4;

    // staging: wave w covers tile rows [w*32, w*32+32), 2 instrs of 1KB
    const bf16* ga0 = A  + (size_t)(m0 + wid * 32 + (lane >> 2)) * K + (lane & 3) * 8;
    const bf16* ga1 = ga0 + (size_t)16 * K;
    const bf16* gb0 = Bm + (size_t)(n0 + wid * 32 + (lane >> 2)) * K + (lane & 3) * 8;
    const bf16* gb1 = gb0 + (size_t)16 * K;
    bf16* la0 = As + wid * 1024;
    bf16* la1 = As + wid * 1024 + 512;
    bf16* lb0 = Bs + wid * 1024;
    bf16* lb1 = Bs + wid * 1024 + 512;

    f32x4 acc[4][4] = {};
    for (int k0 = 0; k0 < K; k0 += 32) {
        gload_lds16(ga0, la0); gload_lds16(ga1, la1);
        gload_lds16(gb0, lb0); gload_lds16(gb1, lb1);
        ga0 += 32; ga1 += 32; gb0 += 32; gb1 += 32;
        __syncthreads();   // compiler drains vmcnt before barrier
        bf16x8 af[4], bq[4];
        #pragma unroll
        for (int m = 0; m < 4; ++m)
            af[m] = *(const bf16x8*)(As + (wr + m * 16 + fr) * 32 + fq * 8);
        #pragma unroll
        for (int n = 0; n < 4; ++n)
            bq[n] = *(const bf16x8*)(Bs + (wc + n * 16 + fr) * 32 + fq * 8);
        #pragma unroll
        for (int m = 0; m < 4; ++m)
            #pragma unroll
            for (int n = 0; n < 4; ++n)
                acc[m][n] = __builtin_amdgcn_mfma_f32_16x16x32_bf16(af[m], bq[n], acc[m][n], 0, 0, 0);
        __syncthreads();
    }

    // C/D layout: col = lane&15, row = (lane>>4)*4 + reg  [m89-verified]
    #pragma unroll
    for (int m = 0; m < 4; ++m) {
        const int row = m0 + wr + m * 16 + fq * 4;
        #pragma unroll
        for (int n = 0; n < 4; ++n) {
            const int col = n0 + wc + n * 16 + fr;
            if (NCHECK && col >= N) continue;
            float bv = BIAS ? bias[col] : 0.f;
            #pragma unroll
            for (int r = 0; r < 4; ++r) {
                float v = acc[m][n][r] + bv;
                if (GELU_) {
                    float u = v;
                    v = 0.5f * u * (1.0f + tanhf(0.7978845608028654f * (u + 0.044715f * u * u * u)));
                }
                if (RES) v += res[(size_t)(row + r) * N + col];
                if (OUTBF16) Cb[(size_t)(row + r) * N + col] = __float2bfloat16(v);
                else         Cf[(size_t)(row + r) * N + col] = v;
            }
        }
    }
}

// ---------------- flash-style attention: 16 q-rows/block, 64-key tiles --------
__global__ __launch_bounds__(256) void attn2_kernel(const float* __restrict__ qkv,
                                                    bf16* __restrict__ out) {
    __shared__ float Ks[64][68];
    __shared__ float Vs[64][68];
    __shared__ float qs[16][68];
    __shared__ float ps[16][64];
    const int nq = TT / 16;
    int bid = blockIdx.x;
    int q0 = (bid % nq) * 16;
    int h = (bid / nq) % HH;
    int b = bid / (nq * HH);
    int tid = threadIdx.x;
    int r = tid >> 4, c = tid & 15;
    {   // stage Q tile (16x64)
        int row = tid >> 4, d4 = (tid & 15) * 4;
        const float* src = qkv + (size_t)(b * TT + q0 + row) * (3 * DD) + h * NHD + d4;
        *(float4*)&qs[row][d4] = *(const float4*)src;
    }
    float m_run = -1e30f, l_run = 0.f;
    float4 o = make_float4(0.f, 0.f, 0.f, 0.f);
    const int t = q0 + r;
    const int ntile = (q0 + 15) / 64 + 1;
    for (int jt = 0; jt < ntile; ++jt) {
        __syncthreads();
        for (int i = tid; i < 64 * 16; i += 256) {   // stage K,V tiles (64x64 each)
            int row = i >> 4, d4 = (i & 15) * 4;
            const float* kp = qkv + (size_t)(b * TT + jt * 64 + row) * (3 * DD) + DD + h * NHD + d4;
            *(float4*)&Ks[row][d4] = *(const float4*)kp;
            *(float4*)&Vs[row][d4] = *(const float4*)(kp + DD);
        }
        __syncthreads();
        float s[4] = {0.f, 0.f, 0.f, 0.f};
        #pragma unroll 4
        for (int d4 = 0; d4 < 64; d4 += 4) {
            float4 qv = *(const float4*)&qs[r][d4];
            #pragma unroll
            for (int jj = 0; jj < 4; ++jj) {
                float4 kv = *(const float4*)&Ks[c + jj * 16][d4];
                s[jj] += qv.x * kv.x + qv.y * kv.y + qv.z * kv.z + qv.w * kv.w;
            }
        }
        float mt = -1e30f;
        #pragma unroll
        for (int jj = 0; jj < 4; ++jj) {
            int j = jt * 64 + c + jj * 16;
            s[jj] = (j <= t) ? s[jj] * 0.125f : -1e30f;
            mt = fmaxf(mt, s[jj]);
        }
        for (int msk = 1; msk <= 8; msk <<= 1) mt = fmaxf(mt, __shfl_xor(mt, msk));
        float m_new = fmaxf(m_run, mt);
        float p[4], pt = 0.f;
        #pragma unroll
        for (int jj = 0; jj < 4; ++jj) { p[jj] = __expf(s[jj] - m_new); pt += p[jj]; }
        for (int msk = 1; msk <= 8; msk <<= 1) pt += __shfl_xor(pt, msk);
        float sc = __expf(m_run - m_new);
        l_run = l_run * sc + pt;
        o.x *= sc; o.y *= sc; o.z *= sc; o.w *= sc;
        #pragma unroll
        for (int jj = 0; jj < 4; ++jj) ps[r][c + jj * 16] = p[jj];
        __syncthreads();
        #pragma unroll 8
        for (int j = 0; j < 64; ++j) {
            float pv = ps[r][j];
            float4 vv = *(const float4*)&Vs[j][c * 4];
            o.x += pv * vv.x; o.y += pv * vv.y; o.z += pv * vv.z; o.w += pv * vv.w;
        }
        m_run = m_new;
    }
    float inv = 1.f / l_run;
    bf16* op = out + (size_t)(b * TT + q0 + r) * DD + h * NHD + c * 4;
    op[0] = __float2bfloat16(o.x * inv);
    op[1] = __float2bfloat16(o.y * inv);
    op[2] = __float2bfloat16(o.z * inv);
    op[3] = __float2bfloat16(o.w * inv);
}

// ---------------- loss ----------------
__global__ void zero_kernel(float* p) { if (threadIdx.x == 0) p[0] = 0.f; }

__global__ void loss_kernel(const float* __restrict__ logits, const int* __restrict__ targets,
                            float* __restrict__ acc) {
    __shared__ float red[256];
    int m = blockIdx.x;
    int tid = threadIdx.x;
    const float* lr = logits + (size_t)m * VV;
    float lmax = -1e30f;
    for (int v = tid; v < VV; v += 256) lmax = fmaxf(lmax, lr[v]);
    red[tid] = lmax; __syncthreads();
    for (int s = 128; s > 0; s >>= 1) { if (tid < s) red[tid] = fmaxf(red[tid], red[tid + s]); __syncthreads(); }
    float mx = red[0];
    __syncthreads();
    float lsum = 0.f;
    for (int v = tid; v < VV; v += 256) lsum += __expf(lr[v] - mx);
    red[tid] = lsum; __syncthreads();
    for (int s = 128; s > 0; s >>= 1) { if (tid < s) red[tid] += red[tid + s]; __syncthreads(); }
    if (tid == 0) {
        float lse = logf(red[0]) + mx;
        atomicAdd(acc, lse - lr[targets[m]]);
    }
}

__global__ void loss_final(const float* __restrict__ acc, float* __restrict__ out) {
    if (threadIdx.x == 0) out[0] = acc[0] * (1.0f / (float)MROWS);
}

// ---------------- launch ----------------
extern "C" void kernel_launch(void* const* d_in, const int* in_sizes, int n_in,
                              void* d_out, int out_size, void* d_ws, size_t ws_size,
                              hipStream_t stream) {
    const int*   idx     = (const int*)d_in[0];
    const int*   targets = (const int*)d_in[1];
    const float* wte     = (const float*)d_in[2];
    const float* wpe     = (const float*)d_in[3];
    const float* ln1_w   = (const float*)d_in[4];
    const float* ln1_b   = (const float*)d_in[5];
    const float* qkv_w   = (const float*)d_in[6];
    const float* qkv_b   = (const float*)d_in[7];
    const float* proj_w  = (const float*)d_in[8];
    const float* proj_b  = (const float*)d_in[9];
    const float* ln2_w   = (const float*)d_in[10];
    const float* ln2_b   = (const float*)d_in[11];
    const float* fc_w    = (const float*)d_in[12];
    const float* fc_b    = (const float*)d_in[13];
    const float* fc2_w   = (const float*)d_in[14];
    const float* fc2_b   = (const float*)d_in[15];
    const float* lnf_w   = (const float*)d_in[16];
    const float* lnf_b   = (const float*)d_in[17];

    float* logits = (float*)d_out;
    float* loss_out = logits + (size_t)MROWS * VV;

    // workspace layout (all 16B-aligned)
    float* x      = (float*)d_ws;                       // 2048*768  fp32
    float* qkvbuf = x + (size_t)MROWS * DD;             // 2048*2304 fp32
    float* lacc   = qkvbuf + (size_t)MROWS * 3 * DD;    // 16 floats
    bf16* hb   = (bf16*)(lacc + 16);                    // 2048*768
    bf16* ab   = hb + (size_t)MROWS * DD;               // 2048*768
    bf16* gb   = ab + (size_t)MROWS * DD;               // 2048*3072
    bf16* wQT  = gb + (size_t)MROWS * 4 * DD;           // 2304*768
    bf16* wPT  = wQT + (size_t)3 * DD * DD;             // 768*768
    bf16* wFT  = wPT + (size_t)DD * DD;                 // 3072*768
    bf16* wF2T = wFT + (size_t)4 * DD * DD;             // 768*3072
    bf16* wteb = wF2T + (size_t)4 * DD * DD;            // 50304*768 (47 pad rows)

    dim3 blk(256);

    cast_kernel<<<2048, blk, 0, stream>>>(wte, wteb, VV * DD / 4);
    embed_kernel<<<MROWS, blk, 0, stream>>>(idx, wte, wpe, x);

    for (int l = 0; l < LL; ++l) {
        const float* l1w = ln1_w + (size_t)l * DD;
        const float* l1b = ln1_b + (size_t)l * DD;
        const float* qw  = qkv_w + (size_t)l * DD * 3 * DD;
        const float* qb  = qkv_b + (size_t)l * 3 * DD;
        const float* pw  = proj_w + (size_t)l * DD * DD;
        const float* pb  = proj_b + (size_t)l * DD;
        const float* l2w = ln2_w + (size_t)l * DD;
        const float* l2b = ln2_b + (size_t)l * DD;
        const float* fw  = fc_w + (size_t)l * DD * 4 * DD;
        const float* fb  = fc_b + (size_t)l * 4 * DD;
        const float* f2w = fc2_w + (size_t)l * 4 * DD * DD;
        const float* f2b = fc2_b + (size_t)l * DD;

        tcast_kernel<<<dim3(3 * DD / 32, DD / 32), blk, 0, stream>>>(qw, wQT, DD, 3 * DD);
        tcast_kernel<<<dim3(DD / 32, DD / 32), blk, 0, stream>>>(pw, wPT, DD, DD);
        tcast_kernel<<<dim3(4 * DD / 32, DD / 32), blk, 0, stream>>>(fw, wFT, DD, 4 * DD);
        tcast_kernel<<<dim3(DD / 32, 4 * DD / 32), blk, 0, stream>>>(f2w, wF2T, 4 * DD, DD);

        ln_kernel<<<MROWS, blk, 0, stream>>>(x, l1w, l1b, hb);

        mgemm<true, false, false, false, false><<<dim3(MROWS / 128, 3 * DD / 128), blk, 0, stream>>>(
            hb, wQT, qb, nullptr, qkvbuf, nullptr, MROWS, 3 * DD, DD);

        attn2_kernel<<<BB * HH * (TT / 16), blk, 0, stream>>>(qkvbuf, ab);

        mgemm<true, false, true, false, false><<<dim3(MROWS / 128, DD / 128), blk, 0, stream>>>(
            ab, wPT, pb, x, x, nullptr, MROWS, DD, DD);

        ln_kernel<<<MROWS, blk, 0, stream>>>(x, l2w, l2b, hb);

        mgemm<true, true, false, true, false><<<dim3(MROWS / 128, 4 * DD / 128), blk, 0, stream>>>(
            hb, wFT, fb, nullptr, nullptr, gb, MROWS, 4 * DD, DD);

        mgemm<true, false, true, false, false><<<dim3(MROWS / 128, DD / 128), blk, 0, stream>>>(
            gb, wF2T, f2b, x, x, nullptr, MROWS, DD, 4 * DD);
    }

    ln_kernel<<<MROWS, blk, 0, stream>>>(x, lnf_w, lnf_b, hb);

    mgemm<false, false, false, false, true><<<dim3(MROWS / 128, VPAD / 128), blk, 0, stream>>>(
        hb, wteb, nullptr, nullptr, logits, nullptr, MROWS, VV, DD);

    zero_kernel<<<1, 64, 0, stream>>>(lacc);
    loss_kernel<<<MROWS, blk, 0, stream>>>(logits, targets, lacc);
    loss_final<<<1, 64, 0, stream>>>(lacc, loss_out);
}

// Round 3
// 3284.800 us; speedup vs baseline: 5.3158x; 1.3303x over previous
//
#include <hip/hip_runtime.h>
#include <hip/hip_bf16.h>
#include <math.h>

#define TT 1024
#define BB 2
#define DD 768
#define HH 12
#define NHD 64
#define LL 12
#define VV 50257
#define MROWS (BB*TT)
#define VPAD 50304

typedef __attribute__((ext_vector_type(4))) float f32x4;
typedef __attribute__((ext_vector_type(8))) __bf16 bf16x8;
typedef __attribute__((ext_vector_type(8))) unsigned short u16x8;
typedef __hip_bfloat16 bf16;

__device__ __forceinline__ void gload_lds16(const bf16* g, bf16* l) {
    __builtin_amdgcn_global_load_lds((const __attribute__((address_space(1))) void*)g,
                                     (__attribute__((address_space(3))) void*)l, 16, 0, 0);
}

// ---------------- embedding (fp32 residual stream) ----------------
__global__ void embed_kernel(const int* __restrict__ idx, const float* __restrict__ wte,
                             const float* __restrict__ wpe, float* __restrict__ x) {
    int m = blockIdx.x;
    int t = m % TT;
    int tok = idx[m];
    const float* wrow = wte + (size_t)tok * DD;
    const float* prow = wpe + (size_t)t * DD;
    float* xrow = x + (size_t)m * DD;
    for (int c = threadIdx.x; c < DD; c += blockDim.x)
        xrow[c] = wrow[c] + prow[c];
}

// ---------------- layernorm: fp32 in -> bf16 out ----------------
__global__ void ln_kernel(const float* __restrict__ x, const float* __restrict__ w,
                          const float* __restrict__ b, bf16* __restrict__ out) {
    __shared__ float red[256];
    int m = blockIdx.x;
    int tid = threadIdx.x;
    const float* xr = x + (size_t)m * DD;
    float v0 = xr[tid], v1 = xr[tid + 256], v2 = xr[tid + 512];
    red[tid] = v0 + v1 + v2;
    __syncthreads();
    for (int s = 128; s > 0; s >>= 1) { if (tid < s) red[tid] += red[tid + s]; __syncthreads(); }
    float mu = red[0] * (1.0f / DD);
    __syncthreads();
    float d0 = v0 - mu, d1 = v1 - mu, d2 = v2 - mu;
    red[tid] = d0 * d0 + d1 * d1 + d2 * d2;
    __syncthreads();
    for (int s = 128; s > 0; s >>= 1) { if (tid < s) red[tid] += red[tid + s]; __syncthreads(); }
    float rstd = rsqrtf(red[0] * (1.0f / DD) + 1e-5f);
    bf16* orow = out + (size_t)m * DD;
    orow[tid]       = __float2bfloat16(d0 * rstd * w[tid]       + b[tid]);
    orow[tid + 256] = __float2bfloat16(d1 * rstd * w[tid + 256] + b[tid + 256]);
    orow[tid + 512] = __float2bfloat16(d2 * rstd * w[tid + 512] + b[tid + 512]);
}

// ---------------- fp32 -> bf16 cast (wte) ----------------
__global__ void cast_kernel(const float* __restrict__ src, bf16* __restrict__ dst, int n4) {
    int stride = gridDim.x * blockDim.x;
    for (int i = blockIdx.x * blockDim.x + threadIdx.x; i < n4; i += stride) {
        float4 v = *(const float4*)(src + (size_t)i * 4);
        bf16* d = dst + (size_t)i * 4;
        d[0] = __float2bfloat16(v.x); d[1] = __float2bfloat16(v.y);
        d[2] = __float2bfloat16(v.z); d[3] = __float2bfloat16(v.w);
    }
}

// ---------------- W[K,N] fp32 -> Wt[N,K] bf16 ----------------
__global__ void tcast_kernel(const float* __restrict__ W, bf16* __restrict__ Wt, int K, int N) {
    __shared__ float t[32][33];
    int n0 = blockIdx.x * 32, k0 = blockIdx.y * 32;
    int c = threadIdx.x & 31, g = threadIdx.x >> 5;
    #pragma unroll
    for (int i = 0; i < 4; ++i) {
        int k = g * 4 + i;
        t[k][c] = W[(size_t)(k0 + k) * N + n0 + c];
    }
    __syncthreads();
    #pragma unroll
    for (int i = 0; i < 4; ++i) {
        int n = g * 4 + i;
        Wt[(size_t)(n0 + n) * K + k0 + c] = __float2bfloat16(t[c][n]);
    }
}

// ---------------- MFMA GEMM: C[M,N] = A[M,K] @ Wt[N,K]^T ----------------
// 128x128 tile, BK=64, 4 waves. T1 XCD swizzle + T2 LDS XOR swizzle
// (pre-swizzled global source, linear global_load_lds dest, swizzled ds_read).
template<bool BIAS, bool GELU_, bool RES, bool OUTBF16, bool NCHECK>
__global__ __launch_bounds__(256, 2) void mgemm(
        const bf16* __restrict__ A, const bf16* __restrict__ Bm,
        const float* __restrict__ bias, const float* __restrict__ res,
        float* __restrict__ Cf, bf16* __restrict__ Cb, int M, int N, int K) {
    __shared__ __align__(16) bf16 As[128 * 64];
    __shared__ __align__(16) bf16 Bs[128 * 64];
    const int tid = threadIdx.x, lane = tid & 63, wid = tid >> 6;
    // XCD-aware bijective swizzle (all grids have nwg % 8 == 0)
    const int nbx = gridDim.x;
    const int nwg = nbx * gridDim.y;
    const int bid = blockIdx.x + nbx * blockIdx.y;
    const int cpx = nwg >> 3;
    const int sw = (bid & 7) * cpx + (bid >> 3);
    const int m0 = (sw % nbx) * 128, n0 = (sw / nbx) * 128;
    const int wr = (wid >> 1) * 64, wc = (wid & 1) * 64;
    const int fr = lane & 15, fq = lane >> 4;
    const int swl = fr & 7;           // row&7 for this lane's fragment rows

    // staging: wave covers rows [wid*32, wid*32+32), 4 instrs/operand/k-tile
    const int srow = wid * 32 + (lane >> 3);
    const int koff = ((lane & 7) ^ (lane >> 3)) * 8;   // pre-swizzled k source
    const bf16* ga = A  + (size_t)(m0 + srow) * K + koff;
    const bf16* gb = Bm + (size_t)(n0 + srow) * K + koff;
    bf16* la = As + wid * 2048 + lane * 8;
    bf16* lb = Bs + wid * 2048 + lane * 8;

    f32x4 acc[4][4] = {};
    for (int k0 = 0; k0 < K; k0 += 64) {
        #pragma unroll
        for (int i = 0; i < 4; ++i) {
            gload_lds16(ga + (size_t)(i * 8) * K, la + i * 512);
            gload_lds16(gb + (size_t)(i * 8) * K, lb + i * 512);
        }
        ga += 64; gb += 64;
        __syncthreads();
        #pragma unroll
        for (int s = 0; s < 2; ++s) {
            const int ks = ((s * 4 + fq) ^ swl) * 8;
            bf16x8 af[4], bq[4];
            #pragma unroll
            for (int m = 0; m < 4; ++m)
                af[m] = *(const bf16x8*)(As + (wr + m * 16 + fr) * 64 + ks);
            #pragma unroll
            for (int n = 0; n < 4; ++n)
                bq[n] = *(const bf16x8*)(Bs + (wc + n * 16 + fr) * 64 + ks);
            #pragma unroll
            for (int m = 0; m < 4; ++m)
                #pragma unroll
                for (int n = 0; n < 4; ++n)
                    acc[m][n] = __builtin_amdgcn_mfma_f32_16x16x32_bf16(af[m], bq[n], acc[m][n], 0, 0, 0);
        }
        __syncthreads();
    }

    #pragma unroll
    for (int m = 0; m < 4; ++m) {
        const int row = m0 + wr + m * 16 + fq * 4;
        #pragma unroll
        for (int n = 0; n < 4; ++n) {
            const int col = n0 + wc + n * 16 + fr;
            if (NCHECK && col >= N) continue;
            float bv = BIAS ? bias[col] : 0.f;
            #pragma unroll
            for (int r = 0; r < 4; ++r) {
                float v = acc[m][n][r] + bv;
                if (GELU_) {
                    float u = v;
                    v = 0.5f * u * (1.0f + tanhf(0.7978845608028654f * (u + 0.044715f * u * u * u)));
                }
                if (RES) v += res[(size_t)(row + r) * N + col];
                if (OUTBF16) Cb[(size_t)(row + r) * N + col] = __float2bfloat16(v);
                else         Cf[(size_t)(row + r) * N + col] = v;
            }
        }
    }
}

// ---------------- MFMA flash attention: 64 q-rows/block, 4 waves x 16 rows ----
__global__ __launch_bounds__(256) void attn3_kernel(const bf16* __restrict__ qkv,
                                                    bf16* __restrict__ out) {
    __shared__ bf16 Vt[64 * 64];        // [d][key], XOR-swizzled
    __shared__ bf16 Ps[4][16 * 64];     // per-wave P [qrow][key], XOR-swizzled
    const int bid = blockIdx.x;
    const int q0 = (bid % (TT / 64)) * 64;
    const int h  = (bid / (TT / 64)) % HH;
    const int b  = bid / ((TT / 64) * HH);
    const int tid = threadIdx.x, lane = tid & 63, wid = tid >> 6;
    const int fr = lane & 15, fq = lane >> 4;
    const size_t rs = 3 * DD;

    // Q fragments in registers (A-frag rows = fr)
    bf16x8 qf[2];
    {
        const bf16* qb = qkv + (size_t)(b * TT + q0 + wid * 16 + fr) * rs + h * NHD;
        qf[0] = *(const bf16x8*)(qb + fq * 8);
        qf[1] = *(const bf16x8*)(qb + 32 + fq * 8);
    }
    float mrun[4] = {-1e30f, -1e30f, -1e30f, -1e30f};
    float lrun[4] = {0.f, 0.f, 0.f, 0.f};
    f32x4 o[4] = {};
    const int vrow = (tid & 31) * 2, kq = tid >> 5;   // V staging assignment
    const int ntile = q0 / 64 + 1;

    for (int jt = 0; jt < ntile; ++jt) {
        __syncthreads();   // prev PV done reading Vt
        {   // stage V transposed + swizzled: Vt[d][key] pairs along key
            const u16x8* vb = (const u16x8*)(qkv + (size_t)(b * TT + jt * 64 + vrow) * rs + 2 * DD + h * NHD + kq * 8);
            u16x8 v0 = vb[0];
            u16x8 v1 = *(const u16x8*)((const bf16*)vb + rs);
            #pragma unroll
            for (int j = 0; j < 8; ++j) {
                int d = kq * 8 + j;
                int e = (d * 64 + vrow) ^ ((d & 7) << 3);
                *(unsigned int*)&Vt[e] = (unsigned int)v0[j] | ((unsigned int)v1[j] << 16);
            }
        }
        // S = Q K^T (K fragments direct from global)
        f32x4 s[4] = {};
        const bf16* kb = qkv + (size_t)(b * TT + jt * 64 + fr) * rs + DD + h * NHD;
        #pragma unroll
        for (int n = 0; n < 4; ++n) {
            bf16x8 k0 = *(const bf16x8*)(kb + (size_t)(n * 16) * rs + fq * 8);
            bf16x8 k1 = *(const bf16x8*)(kb + (size_t)(n * 16) * rs + 32 + fq * 8);
            s[n] = __builtin_amdgcn_mfma_f32_16x16x32_bf16(qf[0], k0, s[n], 0, 0, 0);
            s[n] = __builtin_amdgcn_mfma_f32_16x16x32_bf16(qf[1], k1, s[n], 0, 0, 0);
        }
        // mask + online softmax (rows fq*4+r, cols n*16+fr)
        float mt[4] = {-1e30f, -1e30f, -1e30f, -1e30f};
        #pragma unroll
        for (int n = 0; n < 4; ++n) {
            int colg = jt * 64 + n * 16 + fr;
            #pragma unroll
            for (int r = 0; r < 4; ++r) {
                int rowg = q0 + wid * 16 + fq * 4 + r;
                float v = s[n][r] * 0.125f;
                if (colg > rowg) v = -1e30f;
                s[n][r] = v;
                mt[r] = fmaxf(mt[r], v);
            }
        }
        #pragma unroll
        for (int msk = 1; msk <= 8; msk <<= 1)
            #pragma unroll
            for (int r = 0; r < 4; ++r) mt[r] = fmaxf(mt[r], __shfl_xor(mt[r], msk));
        float sc[4], pt[4] = {0.f, 0.f, 0.f, 0.f};
        #pragma unroll
        for (int r = 0; r < 4; ++r) {
            float mn = fmaxf(mrun[r], mt[r]);
            sc[r] = __expf(mrun[r] - mn);
            mrun[r] = mn;
        }
        #pragma unroll
        for (int n = 0; n < 4; ++n)
            #pragma unroll
            for (int r = 0; r < 4; ++r) {
                float p = __expf(s[n][r] - mrun[r]);
                s[n][r] = p;
                pt[r] += p;
            }
        #pragma unroll
        for (int msk = 1; msk <= 8; msk <<= 1)
            #pragma unroll
            for (int r = 0; r < 4; ++r) pt[r] += __shfl_xor(pt[r], msk);
        #pragma unroll
        for (int r = 0; r < 4; ++r) lrun[r] = lrun[r] * sc[r] + pt[r];
        #pragma unroll
        for (int n2 = 0; n2 < 4; ++n2)
            #pragma unroll
            for (int r = 0; r < 4; ++r) o[n2][r] *= sc[r];
        // write P to per-wave swizzled LDS (row = fq*4+r, key = n*16+fr)
        #pragma unroll
        for (int n = 0; n < 4; ++n)
            #pragma unroll
            for (int r = 0; r < 4; ++r) {
                int row = fq * 4 + r;
                int e = (row * 64 + n * 16 + fr) ^ ((row & 7) << 3);
                Ps[wid][e] = __float2bfloat16(s[n][r]);
            }
        __syncthreads();   // Vt staged (and P visible; P is wave-local anyway)
        // O += P V  (A-frag rows = fr over this wave's q-rows)
        #pragma unroll
        for (int ks = 0; ks < 2; ++ks) {
            int pe = (fr * 64 + ks * 32 + fq * 8) ^ ((fr & 7) << 3);
            bf16x8 pa = *(const bf16x8*)&Ps[wid][pe];
            #pragma unroll
            for (int n2 = 0; n2 < 4; ++n2) {
                int d = n2 * 16 + fr;
                int ve = (d * 64 + ks * 32 + fq * 8) ^ ((d & 7) << 3);
                bf16x8 vv = *(const bf16x8*)&Vt[ve];
                o[n2] = __builtin_amdgcn_mfma_f32_16x16x32_bf16(pa, vv, o[n2], 0, 0, 0);
            }
        }
    }
    // epilogue: rows fq*4+r, d cols n2*16+fr
    #pragma unroll
    for (int r = 0; r < 4; ++r) {
        float inv = 1.f / lrun[r];
        bf16* op = out + (size_t)(b * TT + q0 + wid * 16 + fq * 4 + r) * DD + h * NHD;
        #pragma unroll
        for (int n2 = 0; n2 < 4; ++n2)
            op[n2 * 16 + fr] = __float2bfloat16(o[n2][r] * inv);
    }
}

// ---------------- loss ----------------
__global__ void zero_kernel(float* p) { if (threadIdx.x == 0) p[0] = 0.f; }

__global__ void loss_kernel(const float* __restrict__ logits, const int* __restrict__ targets,
                            float* __restrict__ acc) {
    __shared__ float red[256];
    int m = blockIdx.x;
    int tid = threadIdx.x;
    const float* lr = logits + (size_t)m * VV;
    float lmax = -1e30f;
    for (int v = tid; v < VV; v += 256) lmax = fmaxf(lmax, lr[v]);
    red[tid] = lmax; __syncthreads();
    for (int s = 128; s > 0; s >>= 1) { if (tid < s) red[tid] = fmaxf(red[tid], red[tid + s]); __syncthreads(); }
    float mx = red[0];
    __syncthreads();
    float lsum = 0.f;
    for (int v = tid; v < VV; v += 256) lsum += __expf(lr[v] - mx);
    red[tid] = lsum; __syncthreads();
    for (int s = 128; s > 0; s >>= 1) { if (tid < s) red[tid] += red[tid + s]; __syncthreads(); }
    if (tid == 0) {
        float lse = logf(red[0]) + mx;
        atomicAdd(acc, lse - lr[targets[m]]);
    }
}

__global__ void loss_final(const float* __restrict__ acc, float* __restrict__ out) {
    if (threadIdx.x == 0) out[0] = acc[0] * (1.0f / (float)MROWS);
}

// ---------------- launch ----------------
extern "C" void kernel_launch(void* const* d_in, const int* in_sizes, int n_in,
                              void* d_out, int out_size, void* d_ws, size_t ws_size,
                              hipStream_t stream) {
    const int*   idx     = (const int*)d_in[0];
    const int*   targets = (const int*)d_in[1];
    const float* wte     = (const float*)d_in[2];
    const float* wpe     = (const float*)d_in[3];
    const float* ln1_w   = (const float*)d_in[4];
    const float* ln1_b   = (const float*)d_in[5];
    const float* qkv_w   = (const float*)d_in[6];
    const float* qkv_b   = (const float*)d_in[7];
    const float* proj_w  = (const float*)d_in[8];
    const float* proj_b  = (const float*)d_in[9];
    const float* ln2_w   = (const float*)d_in[10];
    const float* ln2_b   = (const float*)d_in[11];
    const float* fc_w    = (const float*)d_in[12];
    const float* fc_b    = (const float*)d_in[13];
    const float* fc2_w   = (const float*)d_in[14];
    const float* fc2_b   = (const float*)d_in[15];
    const float* lnf_w   = (const float*)d_in[16];
    const float* lnf_b   = (const float*)d_in[17];

    float* logits = (float*)d_out;
    float* loss_out = logits + (size_t)MROWS * VV;

    const size_t LQ = (size_t)3 * DD * DD, LP = (size_t)DD * DD;
    const size_t LF = (size_t)4 * DD * DD, LF2 = (size_t)4 * DD * DD;
    const size_t LSTRIDE = LQ + LP + LF + LF2;                   // 7,077,888 elems

    float* x    = (float*)d_ws;                                  // [MROWS*DD] fp32
    float* lacc = x + (size_t)MROWS * DD;                        // 16 floats
    bf16* qkvbuf = (bf16*)(lacc + 16);                           // [MROWS*3DD]
    bf16* hb   = qkvbuf + (size_t)MROWS * 3 * DD;                // [MROWS*DD]
    bf16* ab   = hb + (size_t)MROWS * DD;                        // [MROWS*DD]
    bf16* gb   = ab + (size_t)MROWS * DD;                        // [MROWS*4DD]
    bf16* wteb = gb + (size_t)MROWS * 4 * DD;                    // [VPAD*DD]
    bf16* wbase = wteb + (size_t)VPAD * DD;                      // weights

    // hoisted (all layers) vs per-layer weight transposes, by ws_size
    const size_t fixed_bytes = (size_t)((char*)wbase - (char*)d_ws);
    const bool hoist = ws_size >= fixed_bytes + sizeof(bf16) * LSTRIDE * LL;

    dim3 blk(256);
    cast_kernel<<<2048, blk, 0, stream>>>(wte, wteb, VV * DD / 4);
    embed_kernel<<<MROWS, blk, 0, stream>>>(idx, wte, wpe, x);

    if (hoist) {
        for (int l = 0; l < LL; ++l) {
            bf16* wl = wbase + (size_t)l * LSTRIDE;
            tcast_kernel<<<dim3(3 * DD / 32, DD / 32), blk, 0, stream>>>(qkv_w + (size_t)l * LQ, wl, DD, 3 * DD);
            tcast_kernel<<<dim3(DD / 32, DD / 32), blk, 0, stream>>>(proj_w + (size_t)l * LP, wl + LQ, DD, DD);
            tcast_kernel<<<dim3(4 * DD / 32, DD / 32), blk, 0, stream>>>(fc_w + (size_t)l * LF, wl + LQ + LP, DD, 4 * DD);
            tcast_kernel<<<dim3(DD / 32, 4 * DD / 32), blk, 0, stream>>>(fc2_w + (size_t)l * LF2, wl + LQ + LP + LF, 4 * DD, DD);
        }
    }

    for (int l = 0; l < LL; ++l) {
        bf16* wl = hoist ? wbase + (size_t)l * LSTRIDE : wbase;
        bf16* wQT = wl, *wPT = wl + LQ, *wFT = wl + LQ + LP, *wF2T = wl + LQ + LP + LF;
        if (!hoist) {
            tcast_kernel<<<dim3(3 * DD / 32, DD / 32), blk, 0, stream>>>(qkv_w + (size_t)l * LQ, wQT, DD, 3 * DD);
            tcast_kernel<<<dim3(DD / 32, DD / 32), blk, 0, stream>>>(proj_w + (size_t)l * LP, wPT, DD, DD);
            tcast_kernel<<<dim3(4 * DD / 32, DD / 32), blk, 0, stream>>>(fc_w + (size_t)l * LF, wFT, DD, 4 * DD);
            tcast_kernel<<<dim3(DD / 32, 4 * DD / 32), blk, 0, stream>>>(fc2_w + (size_t)l * LF2, wF2T, 4 * DD, DD);
        }

        ln_kernel<<<MROWS, blk, 0, stream>>>(x, ln1_w + (size_t)l * DD, ln1_b + (size_t)l * DD, hb);

        mgemm<true, false, false, true, false><<<dim3(MROWS / 128, 3 * DD / 128), blk, 0, stream>>>(
            hb, wQT, qkv_b + (size_t)l * 3 * DD, nullptr, nullptr, qkvbuf, MROWS, 3 * DD, DD);

        attn3_kernel<<<BB * HH * (TT / 64), blk, 0, stream>>>(qkvbuf, ab);

        mgemm<true, false, true, false, false><<<dim3(MROWS / 128, DD / 128), blk, 0, stream>>>(
            ab, wPT, proj_b + (size_t)l * DD, x, x, nullptr, MROWS, DD, DD);

        ln_kernel<<<MROWS, blk, 0, stream>>>(x, ln2_w + (size_t)l * DD, ln2_b + (size_t)l * DD, hb);

        mgemm<true, true, false, true, false><<<dim3(MROWS / 128, 4 * DD / 128), blk, 0, stream>>>(
            hb, wFT, fc_b + (size_t)l * 4 * DD, nullptr, nullptr, gb, MROWS, 4 * DD, DD);

        mgemm<true, false, true, false, false><<<dim3(MROWS / 128, DD / 128), blk, 0, stream>>>(
            gb, wF2T, fc2_b + (size_t)l * DD, x, x, nullptr, MROWS, DD, 4 * DD);
    }

    ln_kernel<<<MROWS, blk, 0, stream>>>(x, lnf_w, lnf_b, hb);

    mgemm<false, false, false, false, true><<<dim3(MROWS / 128, VPAD / 128), blk, 0, stream>>>(
        hb, wteb, nullptr, nullptr, logits, nullptr, MROWS, VV, DD);

    zero_kernel<<<1, 64, 0, stream>>>(lacc);
    loss_kernel<<<MROWS, blk, 0, stream>>>(logits, targets, lacc);
    loss_final<<<1, 64, 0, stream>>>(lacc, loss_out);
}

// Round 4
// 2819.892 us; speedup vs baseline: 6.1922x; 1.1649x over previous
//
#include <hip/hip_runtime.h>
#include <hip/hip_bf16.h>
#include <math.h>

#define TT 1024
#define BB 2
#define DD 768
#define HH 12
#define NHD 64
#define LL 12
#define VV 50257
#define MROWS (BB*TT)
#define VPAD 50304

typedef __attribute__((ext_vector_type(4))) float f32x4;
typedef __attribute__((ext_vector_type(8))) __bf16 bf16x8;
typedef __attribute__((ext_vector_type(8))) unsigned short u16x8;
typedef __hip_bfloat16 bf16;

__device__ __forceinline__ void gload_lds16(const bf16* g, bf16* l) {
    __builtin_amdgcn_global_load_lds((const __attribute__((address_space(1))) void*)g,
                                     (__attribute__((address_space(3))) void*)l, 16, 0, 0);
}

// ---------------- embedding (fp32 residual stream) ----------------
__global__ void embed_kernel(const int* __restrict__ idx, const float* __restrict__ wte,
                             const float* __restrict__ wpe, float* __restrict__ x) {
    int m = blockIdx.x;
    int t = m % TT;
    int tok = idx[m];
    const float* wrow = wte + (size_t)tok * DD;
    const float* prow = wpe + (size_t)t * DD;
    float* xrow = x + (size_t)m * DD;
    for (int c = threadIdx.x; c < DD; c += blockDim.x)
        xrow[c] = wrow[c] + prow[c];
}

// ---------------- layernorm: fp32 in -> bf16 out ----------------
__global__ void ln_kernel(const float* __restrict__ x, const float* __restrict__ w,
                          const float* __restrict__ b, bf16* __restrict__ out) {
    __shared__ float red[256];
    int m = blockIdx.x;
    int tid = threadIdx.x;
    const float* xr = x + (size_t)m * DD;
    float v0 = xr[tid], v1 = xr[tid + 256], v2 = xr[tid + 512];
    red[tid] = v0 + v1 + v2;
    __syncthreads();
    for (int s = 128; s > 0; s >>= 1) { if (tid < s) red[tid] += red[tid + s]; __syncthreads(); }
    float mu = red[0] * (1.0f / DD);
    __syncthreads();
    float d0 = v0 - mu, d1 = v1 - mu, d2 = v2 - mu;
    red[tid] = d0 * d0 + d1 * d1 + d2 * d2;
    __syncthreads();
    for (int s = 128; s > 0; s >>= 1) { if (tid < s) red[tid] += red[tid + s]; __syncthreads(); }
    float rstd = rsqrtf(red[0] * (1.0f / DD) + 1e-5f);
    bf16* orow = out + (size_t)m * DD;
    orow[tid]       = __float2bfloat16(d0 * rstd * w[tid]       + b[tid]);
    orow[tid + 256] = __float2bfloat16(d1 * rstd * w[tid + 256] + b[tid + 256]);
    orow[tid + 512] = __float2bfloat16(d2 * rstd * w[tid + 512] + b[tid + 512]);
}

// ---------------- fp32 -> bf16 cast (wte) ----------------
__global__ void cast_kernel(const float* __restrict__ src, bf16* __restrict__ dst, int n4) {
    int stride = gridDim.x * blockDim.x;
    for (int i = blockIdx.x * blockDim.x + threadIdx.x; i < n4; i += stride) {
        float4 v = *(const float4*)(src + (size_t)i * 4);
        bf16* d = dst + (size_t)i * 4;
        d[0] = __float2bfloat16(v.x); d[1] = __float2bfloat16(v.y);
        d[2] = __float2bfloat16(v.z); d[3] = __float2bfloat16(v.w);
    }
}

// ---------------- W[K,N] fp32 -> Wt[N,K] bf16 ----------------
__global__ void tcast_kernel(const float* __restrict__ W, bf16* __restrict__ Wt, int K, int N) {
    __shared__ float t[32][33];
    int n0 = blockIdx.x * 32, k0 = blockIdx.y * 32;
    int c = threadIdx.x & 31, g = threadIdx.x >> 5;
    #pragma unroll
    for (int i = 0; i < 4; ++i) {
        int k = g * 4 + i;
        t[k][c] = W[(size_t)(k0 + k) * N + n0 + c];
    }
    __syncthreads();
    #pragma unroll
    for (int i = 0; i < 4; ++i) {
        int n = g * 4 + i;
        Wt[(size_t)(n0 + n) * K + k0 + c] = __float2bfloat16(t[c][n]);
    }
}

// ---------------- MFMA GEMM: C[M,N] = A[M,K] @ Wt[N,K]^T ----------------
// BK=32, double-buffered LDS, counted-vmcnt prefetch (T3-min + T4),
// 2-way LDS chunk swizzle (free), T1 XCD bijective swizzle.
template<int BM, int BN, bool BIAS, bool GELU_, bool RES, bool OUTBF16, bool NCHECK>
__global__ __launch_bounds__(256, 3) void mgemm(
        const bf16* __restrict__ A, const bf16* __restrict__ Bm,
        const float* __restrict__ bias, const float* __restrict__ res,
        float* __restrict__ Cf, bf16* __restrict__ Cb, int M, int N, int K) {
    constexpr int WM = BM / 32, WN = BN / 32;     // fragment repeats per wave
    constexpr int RA = BM / 64, RB = BN / 64;     // gload instrs per thread per operand
    constexpr int NL = RA + RB;                   // loads in flight for next tile
    __shared__ __align__(16) bf16 As[2][BM * 32];
    __shared__ __align__(16) bf16 Bs[2][BN * 32];
    const int tid = threadIdx.x, lane = tid & 63, wid = tid >> 6;
    const int nbx = gridDim.x;
    const int nwg = nbx * gridDim.y;
    const int bidl = blockIdx.x + nbx * blockIdx.y;
    const int cpx = nwg >> 3;
    const int sw = (bidl & 7) * cpx + (bidl >> 3);
    const int m0 = (sw % nbx) * BM, n0 = (sw / nbx) * BN;
    const int wr = (wid >> 1) * (BM / 2), wc = (wid & 1) * (BN / 2);
    const int fr = lane & 15, fq = lane >> 4;

    // staging: wave w covers rows [w*16 + i*64); thread: row=lane>>2, chunk=lane&3.
    // global k-chunk pre-swizzled: c_src = c_phys ^ ((row>>1)&3)  (involution)
    const int ksrc = ((lane & 3) ^ ((lane >> 3) & 3)) * 8;
    const bf16* gA = A  + (size_t)(m0 + wid * 16 + (lane >> 2)) * K + ksrc;
    const bf16* gB = Bm + (size_t)(n0 + wid * 16 + (lane >> 2)) * K + ksrc;
    bf16* lA = &As[0][0] + wid * 512 + lane * 8;
    bf16* lB = &Bs[0][0] + wid * 512 + lane * 8;
    // fragment read: logical chunk fq at row ..+fr -> phys chunk fq ^ ((fr>>1)&3)
    const int kph = (fq ^ ((fr >> 1) & 3)) * 8;

    f32x4 acc[WM][WN] = {};
    const int nt = K / 32;

    #pragma unroll
    for (int i = 0; i < RA; ++i) gload_lds16(gA + (size_t)(i * 64) * K, lA + i * 2048);
    #pragma unroll
    for (int i = 0; i < RB; ++i) gload_lds16(gB + (size_t)(i * 64) * K, lB + i * 2048);

    for (int t = 0; t < nt; ++t) {
        const int cur = t & 1;
        if (t + 1 < nt) {   // prefetch next K-tile into other buffer
            const bf16* pA = gA + (t + 1) * 32;
            const bf16* pB = gB + (t + 1) * 32;
            bf16* dA = lA + (cur ^ 1) * (BM * 32);
            bf16* dB = lB + (cur ^ 1) * (BN * 32);
            #pragma unroll
            for (int i = 0; i < RA; ++i) gload_lds16(pA + (size_t)(i * 64) * K, dA + i * 2048);
            #pragma unroll
            for (int i = 0; i < RB; ++i) gload_lds16(pB + (size_t)(i * 64) * K, dB + i * 2048);
            asm volatile("s_waitcnt vmcnt(%0)" :: "i"(NL) : "memory");
        } else {
            asm volatile("s_waitcnt vmcnt(0)" ::: "memory");
        }
        __builtin_amdgcn_s_barrier();          // buf[cur] staged for all waves
        __builtin_amdgcn_sched_barrier(0);
        const bf16* abase = &As[cur][0];
        const bf16* bbase = &Bs[cur][0];
        bf16x8 af[WM], bq[WN];
        #pragma unroll
        for (int m = 0; m < WM; ++m)
            af[m] = *(const bf16x8*)(abase + (wr + m * 16 + fr) * 32 + kph);
        #pragma unroll
        for (int n = 0; n < WN; ++n)
            bq[n] = *(const bf16x8*)(bbase + (wc + n * 16 + fr) * 32 + kph);
        #pragma unroll
        for (int m = 0; m < WM; ++m)
            #pragma unroll
            for (int n = 0; n < WN; ++n)
                acc[m][n] = __builtin_amdgcn_mfma_f32_16x16x32_bf16(af[m], bq[n], acc[m][n], 0, 0, 0);
        __builtin_amdgcn_sched_barrier(0);
        __builtin_amdgcn_s_barrier();          // all waves done reading buf[cur]
    }

    #pragma unroll
    for (int m = 0; m < WM; ++m) {
        const int row = m0 + wr + m * 16 + fq * 4;
        #pragma unroll
        for (int n = 0; n < WN; ++n) {
            const int col = n0 + wc + n * 16 + fr;
            if (NCHECK && col >= N) continue;
            float bv = BIAS ? bias[col] : 0.f;
            #pragma unroll
            for (int r = 0; r < 4; ++r) {
                float v = acc[m][n][r] + bv;
                if (GELU_) {
                    float u = v;
                    v = 0.5f * u * (1.0f + tanhf(0.7978845608028654f * (u + 0.044715f * u * u * u)));
                }
                if (RES) v += res[(size_t)(row + r) * N + col];
                if (OUTBF16) Cb[(size_t)(row + r) * N + col] = __float2bfloat16(v);
                else         Cf[(size_t)(row + r) * N + col] = v;
            }
        }
    }
}

// ---------------- MFMA flash attention: 64 q-rows/block, 4 waves x 16 rows ----
__global__ __launch_bounds__(256) void attn3_kernel(const bf16* __restrict__ qkv,
                                                    bf16* __restrict__ out) {
    __shared__ bf16 Vt[64 * 64];
    __shared__ bf16 Ps[4][16 * 64];
    const int bid = blockIdx.x;
    const int q0 = (bid % (TT / 64)) * 64;
    const int h  = (bid / (TT / 64)) % HH;
    const int b  = bid / ((TT / 64) * HH);
    const int tid = threadIdx.x, lane = tid & 63, wid = tid >> 6;
    const int fr = lane & 15, fq = lane >> 4;
    const size_t rs = 3 * DD;

    bf16x8 qf[2];
    {
        const bf16* qb = qkv + (size_t)(b * TT + q0 + wid * 16 + fr) * rs + h * NHD;
        qf[0] = *(const bf16x8*)(qb + fq * 8);
        qf[1] = *(const bf16x8*)(qb + 32 + fq * 8);
    }
    float mrun[4] = {-1e30f, -1e30f, -1e30f, -1e30f};
    float lrun[4] = {0.f, 0.f, 0.f, 0.f};
    f32x4 o[4] = {};
    const int vrow = (tid & 31) * 2, kq = tid >> 5;
    const int ntile = q0 / 64 + 1;

    for (int jt = 0; jt < ntile; ++jt) {
        __syncthreads();
        {
            const u16x8* vb = (const u16x8*)(qkv + (size_t)(b * TT + jt * 64 + vrow) * rs + 2 * DD + h * NHD + kq * 8);
            u16x8 v0 = vb[0];
            u16x8 v1 = *(const u16x8*)((const bf16*)vb + rs);
            #pragma unroll
            for (int j = 0; j < 8; ++j) {
                int d = kq * 8 + j;
                int e = (d * 64 + vrow) ^ ((d & 7) << 3);
                *(unsigned int*)&Vt[e] = (unsigned int)v0[j] | ((unsigned int)v1[j] << 16);
            }
        }
        f32x4 s[4] = {};
        const bf16* kb = qkv + (size_t)(b * TT + jt * 64 + fr) * rs + DD + h * NHD;
        #pragma unroll
        for (int n = 0; n < 4; ++n) {
            bf16x8 k0 = *(const bf16x8*)(kb + (size_t)(n * 16) * rs + fq * 8);
            bf16x8 k1 = *(const bf16x8*)(kb + (size_t)(n * 16) * rs + 32 + fq * 8);
            s[n] = __builtin_amdgcn_mfma_f32_16x16x32_bf16(qf[0], k0, s[n], 0, 0, 0);
            s[n] = __builtin_amdgcn_mfma_f32_16x16x32_bf16(qf[1], k1, s[n], 0, 0, 0);
        }
        float mt[4] = {-1e30f, -1e30f, -1e30f, -1e30f};
        #pragma unroll
        for (int n = 0; n < 4; ++n) {
            int colg = jt * 64 + n * 16 + fr;
            #pragma unroll
            for (int r = 0; r < 4; ++r) {
                int rowg = q0 + wid * 16 + fq * 4 + r;
                float v = s[n][r] * 0.125f;
                if (colg > rowg) v = -1e30f;
                s[n][r] = v;
                mt[r] = fmaxf(mt[r], v);
            }
        }
        #pragma unroll
        for (int msk = 1; msk <= 8; msk <<= 1)
            #pragma unroll
            for (int r = 0; r < 4; ++r) mt[r] = fmaxf(mt[r], __shfl_xor(mt[r], msk));
        float sc[4], pt[4] = {0.f, 0.f, 0.f, 0.f};
        #pragma unroll
        for (int r = 0; r < 4; ++r) {
            float mn = fmaxf(mrun[r], mt[r]);
            sc[r] = __expf(mrun[r] - mn);
            mrun[r] = mn;
        }
        #pragma unroll
        for (int n = 0; n < 4; ++n)
            #pragma unroll
            for (int r = 0; r < 4; ++r) {
                float p = __expf(s[n][r] - mrun[r]);
                s[n][r] = p;
                pt[r] += p;
            }
        #pragma unroll
        for (int msk = 1; msk <= 8; msk <<= 1)
            #pragma unroll
            for (int r = 0; r < 4; ++r) pt[r] += __shfl_xor(pt[r], msk);
        #pragma unroll
        for (int r = 0; r < 4; ++r) lrun[r] = lrun[r] * sc[r] + pt[r];
        #pragma unroll
        for (int n2 = 0; n2 < 4; ++n2)
            #pragma unroll
            for (int r = 0; r < 4; ++r) o[n2][r] *= sc[r];
        #pragma unroll
        for (int n = 0; n < 4; ++n)
            #pragma unroll
            for (int r = 0; r < 4; ++r) {
                int row = fq * 4 + r;
                int e = (row * 64 + n * 16 + fr) ^ ((row & 7) << 3);
                Ps[wid][e] = __float2bfloat16(s[n][r]);
            }
        __syncthreads();
        #pragma unroll
        for (int ks = 0; ks < 2; ++ks) {
            int pe = (fr * 64 + ks * 32 + fq * 8) ^ ((fr & 7) << 3);
            bf16x8 pa = *(const bf16x8*)&Ps[wid][pe];
            #pragma unroll
            for (int n2 = 0; n2 < 4; ++n2) {
                int d = n2 * 16 + fr;
                int ve = (d * 64 + ks * 32 + fq * 8) ^ ((d & 7) << 3);
                bf16x8 vv = *(const bf16x8*)&Vt[ve];
                o[n2] = __builtin_amdgcn_mfma_f32_16x16x32_bf16(pa, vv, o[n2], 0, 0, 0);
            }
        }
    }
    #pragma unroll
    for (int r = 0; r < 4; ++r) {
        float inv = 1.f / lrun[r];
        bf16* op = out + (size_t)(b * TT + q0 + wid * 16 + fq * 4 + r) * DD + h * NHD;
        #pragma unroll
        for (int n2 = 0; n2 < 4; ++n2)
            op[n2 * 16 + fr] = __float2bfloat16(o[n2][r] * inv);
    }
}

// ---------------- loss ----------------
__global__ void zero_kernel(float* p) { if (threadIdx.x == 0) p[0] = 0.f; }

__global__ void loss_kernel(const float* __restrict__ logits, const int* __restrict__ targets,
                            float* __restrict__ acc) {
    __shared__ float red[256];
    int m = blockIdx.x;
    int tid = threadIdx.x;
    const float* lr = logits + (size_t)m * VV;
    float lmax = -1e30f;
    for (int v = tid; v < VV; v += 256) lmax = fmaxf(lmax, lr[v]);
    red[tid] = lmax; __syncthreads();
    for (int s = 128; s > 0; s >>= 1) { if (tid < s) red[tid] = fmaxf(red[tid], red[tid + s]); __syncthreads(); }
    float mx = red[0];
    __syncthreads();
    float lsum = 0.f;
    for (int v = tid; v < VV; v += 256) lsum += __expf(lr[v] - mx);
    red[tid] = lsum; __syncthreads();
    for (int s = 128; s > 0; s >>= 1) { if (tid < s) red[tid] += red[tid + s]; __syncthreads(); }
    if (tid == 0) {
        float lse = logf(red[0]) + mx;
        atomicAdd(acc, lse - lr[targets[m]]);
    }
}

__global__ void loss_final(const float* __restrict__ acc, float* __restrict__ out) {
    if (threadIdx.x == 0) out[0] = acc[0] * (1.0f / (float)MROWS);
}

// ---------------- launch ----------------
extern "C" void kernel_launch(void* const* d_in, const int* in_sizes, int n_in,
                              void* d_out, int out_size, void* d_ws, size_t ws_size,
                              hipStream_t stream) {
    const int*   idx     = (const int*)d_in[0];
    const int*   targets = (const int*)d_in[1];
    const float* wte     = (const float*)d_in[2];
    const float* wpe     = (const float*)d_in[3];
    const float* ln1_w   = (const float*)d_in[4];
    const float* ln1_b   = (const float*)d_in[5];
    const float* qkv_w   = (const float*)d_in[6];
    const float* qkv_b   = (const float*)d_in[7];
    const float* proj_w  = (const float*)d_in[8];
    const float* proj_b  = (const float*)d_in[9];
    const float* ln2_w   = (const float*)d_in[10];
    const float* ln2_b   = (const float*)d_in[11];
    const float* fc_w    = (const float*)d_in[12];
    const float* fc_b    = (const float*)d_in[13];
    const float* fc2_w   = (const float*)d_in[14];
    const float* fc2_b   = (const float*)d_in[15];
    const float* lnf_w   = (const float*)d_in[16];
    const float* lnf_b   = (const float*)d_in[17];

    float* logits = (float*)d_out;
    float* loss_out = logits + (size_t)MROWS * VV;

    const size_t LQ = (size_t)3 * DD * DD, LP = (size_t)DD * DD;
    const size_t LF = (size_t)4 * DD * DD, LF2 = (size_t)4 * DD * DD;
    const size_t LSTRIDE = LQ + LP + LF + LF2;

    float* x    = (float*)d_ws;
    float* lacc = x + (size_t)MROWS * DD;
    bf16* qkvbuf = (bf16*)(lacc + 16);
    bf16* hb   = qkvbuf + (size_t)MROWS * 3 * DD;
    bf16* ab   = hb + (size_t)MROWS * DD;
    bf16* gb   = ab + (size_t)MROWS * DD;
    bf16* wteb = gb + (size_t)MROWS * 4 * DD;
    bf16* wbase = wteb + (size_t)VPAD * DD;

    const size_t fixed_bytes = (size_t)((char*)wbase - (char*)d_ws);
    const bool hoist = ws_size >= fixed_bytes + sizeof(bf16) * LSTRIDE * LL;

    dim3 blk(256);
    cast_kernel<<<2048, blk, 0, stream>>>(wte, wteb, VV * DD / 4);
    embed_kernel<<<MROWS, blk, 0, stream>>>(idx, wte, wpe, x);

    if (hoist) {
        for (int l = 0; l < LL; ++l) {
            bf16* wl = wbase + (size_t)l * LSTRIDE;
            tcast_kernel<<<dim3(3 * DD / 32, DD / 32), blk, 0, stream>>>(qkv_w + (size_t)l * LQ, wl, DD, 3 * DD);
            tcast_kernel<<<dim3(DD / 32, DD / 32), blk, 0, stream>>>(proj_w + (size_t)l * LP, wl + LQ, DD, DD);
            tcast_kernel<<<dim3(4 * DD / 32, DD / 32), blk, 0, stream>>>(fc_w + (size_t)l * LF, wl + LQ + LP, DD, 4 * DD);
            tcast_kernel<<<dim3(DD / 32, 4 * DD / 32), blk, 0, stream>>>(fc2_w + (size_t)l * LF2, wl + LQ + LP + LF, 4 * DD, DD);
        }
    }

    for (int l = 0; l < LL; ++l) {
        bf16* wl = hoist ? wbase + (size_t)l * LSTRIDE : wbase;
        bf16* wQT = wl, *wPT = wl + LQ, *wFT = wl + LQ + LP, *wF2T = wl + LQ + LP + LF;
        if (!hoist) {
            tcast_kernel<<<dim3(3 * DD / 32, DD / 32), blk, 0, stream>>>(qkv_w + (size_t)l * LQ, wQT, DD, 3 * DD);
            tcast_kernel<<<dim3(DD / 32, DD / 32), blk, 0, stream>>>(proj_w + (size_t)l * LP, wPT, DD, DD);
            tcast_kernel<<<dim3(4 * DD / 32, DD / 32), blk, 0, stream>>>(fc_w + (size_t)l * LF, wFT, DD, 4 * DD);
            tcast_kernel<<<dim3(DD / 32, 4 * DD / 32), blk, 0, stream>>>(fc2_w + (size_t)l * LF2, wF2T, 4 * DD, DD);
        }

        ln_kernel<<<MROWS, blk, 0, stream>>>(x, ln1_w + (size_t)l * DD, ln1_b + (size_t)l * DD, hb);

        mgemm<128, 128, true, false, false, true, false><<<dim3(MROWS / 128, 3 * DD / 128), blk, 0, stream>>>(
            hb, wQT, qkv_b + (size_t)l * 3 * DD, nullptr, nullptr, qkvbuf, MROWS, 3 * DD, DD);

        attn3_kernel<<<BB * HH * (TT / 64), blk, 0, stream>>>(qkvbuf, ab);

        mgemm<64, 64, true, false, true, false, false><<<dim3(MROWS / 64, DD / 64), blk, 0, stream>>>(
            ab, wPT, proj_b + (size_t)l * DD, x, x, nullptr, MROWS, DD, DD);

        ln_kernel<<<MROWS, blk, 0, stream>>>(x, ln2_w + (size_t)l * DD, ln2_b + (size_t)l * DD, hb);

        mgemm<128, 128, true, true, false, true, false><<<dim3(MROWS / 128, 4 * DD / 128), blk, 0, stream>>>(
            hb, wFT, fc_b + (size_t)l * 4 * DD, nullptr, nullptr, gb, MROWS, 4 * DD, DD);

        mgemm<64, 64, true, false, true, false, false><<<dim3(MROWS / 64, DD / 64), blk, 0, stream>>>(
            gb, wF2T, fc2_b + (size_t)l * DD, x, x, nullptr, MROWS, DD, 4 * DD);
    }

    ln_kernel<<<MROWS, blk, 0, stream>>>(x, lnf_w, lnf_b, hb);

    mgemm<128, 128, false, false, false, false, true><<<dim3(MROWS / 128, VPAD / 128), blk, 0, stream>>>(
        hb, wteb, nullptr, nullptr, logits, nullptr, MROWS, VV, DD);

    zero_kernel<<<1, 64, 0, stream>>>(lacc);
    loss_kernel<<<MROWS, blk, 0, stream>>>(logits, targets, lacc);
    loss_final<<<1, 64, 0, stream>>>(lacc, loss_out);
}

// Round 5
// 2600.023 us; speedup vs baseline: 6.7159x; 1.0846x over previous
//
#include <hip/hip_runtime.h>
#include <hip/hip_bf16.h>
#include <math.h>

#define TT 1024
#define BB 2
#define DD 768
#define HH 12
#define NHD 64
#define LL 12
#define VV 50257
#define MROWS (BB*TT)
#define VPAD 50304

typedef __attribute__((ext_vector_type(4))) float f32x4;
typedef __attribute__((ext_vector_type(8))) __bf16 bf16x8;
typedef __attribute__((ext_vector_type(8))) unsigned short u16x8;
typedef __hip_bfloat16 bf16;

__device__ __forceinline__ void gload_lds16(const bf16* g, bf16* l) {
    __builtin_amdgcn_global_load_lds((const __attribute__((address_space(1))) void*)g,
                                     (__attribute__((address_space(3))) void*)l, 16, 0, 0);
}

// ---------------- embedding (fp32 residual stream) ----------------
__global__ void embed_kernel(const int* __restrict__ idx, const float* __restrict__ wte,
                             const float* __restrict__ wpe, float* __restrict__ x) {
    int m = blockIdx.x;
    int t = m % TT;
    int tok = idx[m];
    const float* wrow = wte + (size_t)tok * DD;
    const float* prow = wpe + (size_t)t * DD;
    float* xrow = x + (size_t)m * DD;
    for (int c = threadIdx.x; c < DD; c += blockDim.x)
        xrow[c] = wrow[c] + prow[c];
}

// ---------------- layernorm: fp32 in -> bf16 out ----------------
__global__ void ln_kernel(const float* __restrict__ x, const float* __restrict__ w,
                          const float* __restrict__ b, bf16* __restrict__ out) {
    __shared__ float red[256];
    int m = blockIdx.x;
    int tid = threadIdx.x;
    const float* xr = x + (size_t)m * DD;
    float v0 = xr[tid], v1 = xr[tid + 256], v2 = xr[tid + 512];
    red[tid] = v0 + v1 + v2;
    __syncthreads();
    for (int s = 128; s > 0; s >>= 1) { if (tid < s) red[tid] += red[tid + s]; __syncthreads(); }
    float mu = red[0] * (1.0f / DD);
    __syncthreads();
    float d0 = v0 - mu, d1 = v1 - mu, d2 = v2 - mu;
    red[tid] = d0 * d0 + d1 * d1 + d2 * d2;
    __syncthreads();
    for (int s = 128; s > 0; s >>= 1) { if (tid < s) red[tid] += red[tid + s]; __syncthreads(); }
    float rstd = rsqrtf(red[0] * (1.0f / DD) + 1e-5f);
    bf16* orow = out + (size_t)m * DD;
    orow[tid]       = __float2bfloat16(d0 * rstd * w[tid]       + b[tid]);
    orow[tid + 256] = __float2bfloat16(d1 * rstd * w[tid + 256] + b[tid + 256]);
    orow[tid + 512] = __float2bfloat16(d2 * rstd * w[tid + 512] + b[tid + 512]);
}

// ---------------- fp32 -> bf16 cast (wte) ----------------
__global__ void cast_kernel(const float* __restrict__ src, bf16* __restrict__ dst, int n4) {
    int stride = gridDim.x * blockDim.x;
    for (int i = blockIdx.x * blockDim.x + threadIdx.x; i < n4; i += stride) {
        float4 v = *(const float4*)(src + (size_t)i * 4);
        bf16* d = dst + (size_t)i * 4;
        d[0] = __float2bfloat16(v.x); d[1] = __float2bfloat16(v.y);
        d[2] = __float2bfloat16(v.z); d[3] = __float2bfloat16(v.w);
    }
}

// ---------------- batched W[K,N] fp32 -> Wt[N,K] bf16 (layer = blockIdx.z) ----
__global__ void tcast_kernel(const float* __restrict__ W, bf16* __restrict__ Wt,
                             int K, int N, size_t wstride, size_t tstride) {
    W  += (size_t)blockIdx.z * wstride;
    Wt += (size_t)blockIdx.z * tstride;
    __shared__ float t[32][33];
    int n0 = blockIdx.x * 32, k0 = blockIdx.y * 32;
    int c = threadIdx.x & 31, g = threadIdx.x >> 5;
    #pragma unroll
    for (int i = 0; i < 4; ++i) {
        int k = g * 4 + i;
        t[k][c] = W[(size_t)(k0 + k) * N + n0 + c];
    }
    __syncthreads();
    #pragma unroll
    for (int i = 0; i < 4; ++i) {
        int n = g * 4 + i;
        Wt[(size_t)(n0 + n) * K + k0 + c] = __float2bfloat16(t[c][n]);
    }
}

// ---------------- MFMA GEMM: C[M,N] = A[M,K] @ Wt[N,K]^T ----------------
// BK=32, 3-buffer LDS, depth-2 prefetch with counted vmcnt (T3/T4),
// 2-way LDS chunk swizzle (free), T1 XCD bijective swizzle.
template<int BM, int BN, bool BIAS, bool GELU_, bool RES, bool OUTBF16, bool NCHECK>
__global__ __launch_bounds__(256, 3) void mgemm(
        const bf16* __restrict__ A, const bf16* __restrict__ Bm,
        const float* __restrict__ bias, const float* __restrict__ res,
        float* __restrict__ Cf, bf16* __restrict__ Cb, int M, int N, int K) {
    constexpr int WM = BM / 32, WN = BN / 32;     // fragment repeats per wave
    constexpr int RA = BM / 64, RB = BN / 64;     // gload instrs per thread per operand
    constexpr int NL = RA + RB;                   // loads per tile per thread
    __shared__ __align__(16) bf16 As[3][BM * 32];
    __shared__ __align__(16) bf16 Bs[3][BN * 32];
    const int tid = threadIdx.x, lane = tid & 63, wid = tid >> 6;
    const int nbx = gridDim.x;
    const int nwg = nbx * gridDim.y;
    const int bidl = blockIdx.x + nbx * blockIdx.y;
    const int cpx = nwg >> 3;
    const int sw = (bidl & 7) * cpx + (bidl >> 3);
    const int m0 = (sw % nbx) * BM, n0 = (sw / nbx) * BN;
    const int wr = (wid >> 1) * (BM / 2), wc = (wid & 1) * (BN / 2);
    const int fr = lane & 15, fq = lane >> 4;

    // staging: row = wid*16 + (lane>>2) (+i*64); global k-chunk pre-swizzled
    const int ksrc = ((lane & 3) ^ ((lane >> 3) & 3)) * 8;
    const bf16* gA = A  + (size_t)(m0 + wid * 16 + (lane >> 2)) * K + ksrc;
    const bf16* gB = Bm + (size_t)(n0 + wid * 16 + (lane >> 2)) * K + ksrc;
    const int kph = (fq ^ ((fr >> 1) & 3)) * 8;   // fragment phys chunk

    const int nt = K / 32;
    auto stage = [&](int tile) {
        bf16* dA = &As[tile % 3][0] + wid * 512 + lane * 8;
        bf16* dB = &Bs[tile % 3][0] + wid * 512 + lane * 8;
        const bf16* pA = gA + tile * 32;
        const bf16* pB = gB + tile * 32;
        #pragma unroll
        for (int i = 0; i < RA; ++i) gload_lds16(pA + (size_t)(i * 64) * K, dA + i * 2048);
        #pragma unroll
        for (int i = 0; i < RB; ++i) gload_lds16(pB + (size_t)(i * 64) * K, dB + i * 2048);
    };

    f32x4 acc[WM][WN] = {};
    stage(0);
    if (nt > 1) stage(1);

    for (int t = 0; t < nt; ++t) {
        if (t + 2 < nt) stage(t + 2);
        const int rem = nt - 1 - t;
        if (rem >= 2)      asm volatile("s_waitcnt vmcnt(%0)" :: "i"(2 * NL) : "memory");
        else if (rem == 1) asm volatile("s_waitcnt vmcnt(%0)" :: "i"(NL) : "memory");
        else               asm volatile("s_waitcnt vmcnt(0)" ::: "memory");
        __builtin_amdgcn_s_barrier();
        __builtin_amdgcn_sched_barrier(0);
        const bf16* abase = &As[t % 3][0];
        const bf16* bbase = &Bs[t % 3][0];
        bf16x8 af[WM], bq[WN];
        #pragma unroll
        for (int m = 0; m < WM; ++m)
            af[m] = *(const bf16x8*)(abase + (wr + m * 16 + fr) * 32 + kph);
        #pragma unroll
        for (int n = 0; n < WN; ++n)
            bq[n] = *(const bf16x8*)(bbase + (wc + n * 16 + fr) * 32 + kph);
        #pragma unroll
        for (int m = 0; m < WM; ++m)
            #pragma unroll
            for (int n = 0; n < WN; ++n)
                acc[m][n] = __builtin_amdgcn_mfma_f32_16x16x32_bf16(af[m], bq[n], acc[m][n], 0, 0, 0);
        __builtin_amdgcn_sched_barrier(0);
        __builtin_amdgcn_s_barrier();
    }

    #pragma unroll
    for (int m = 0; m < WM; ++m) {
        const int row = m0 + wr + m * 16 + fq * 4;
        #pragma unroll
        for (int n = 0; n < WN; ++n) {
            const int col = n0 + wc + n * 16 + fr;
            if (NCHECK && col >= N) continue;
            float bv = BIAS ? bias[col] : 0.f;
            #pragma unroll
            for (int r = 0; r < 4; ++r) {
                float v = acc[m][n][r] + bv;
                if (GELU_) {
                    float u = v;
                    v = 0.5f * u * (1.0f + tanhf(0.7978845608028654f * (u + 0.044715f * u * u * u)));
                }
                if (RES) v += res[(size_t)(row + r) * N + col];
                if (OUTBF16) Cb[(size_t)(row + r) * N + col] = __float2bfloat16(v);
                else         Cf[(size_t)(row + r) * N + col] = v;
            }
        }
    }
}

// ---------------- MFMA flash attention: 64 q-rows/block, 4 waves x 16 rows ----
__global__ __launch_bounds__(256) void attn3_kernel(const bf16* __restrict__ qkv,
                                                    bf16* __restrict__ out) {
    __shared__ bf16 Vt[64 * 64];
    __shared__ bf16 Ps[4][16 * 64];
    const int bid = blockIdx.x;
    const int q0 = (bid % (TT / 64)) * 64;
    const int h  = (bid / (TT / 64)) % HH;
    const int b  = bid / ((TT / 64) * HH);
    const int tid = threadIdx.x, lane = tid & 63, wid = tid >> 6;
    const int fr = lane & 15, fq = lane >> 4;
    const size_t rs = 3 * DD;

    bf16x8 qf[2];
    {
        const bf16* qb = qkv + (size_t)(b * TT + q0 + wid * 16 + fr) * rs + h * NHD;
        qf[0] = *(const bf16x8*)(qb + fq * 8);
        qf[1] = *(const bf16x8*)(qb + 32 + fq * 8);
    }
    float mrun[4] = {-1e30f, -1e30f, -1e30f, -1e30f};
    float lrun[4] = {0.f, 0.f, 0.f, 0.f};
    f32x4 o[4] = {};
    const int vrow = (tid & 31) * 2, kq = tid >> 5;
    const int ntile = q0 / 64 + 1;

    for (int jt = 0; jt < ntile; ++jt) {
        __syncthreads();
        {
            const u16x8* vb = (const u16x8*)(qkv + (size_t)(b * TT + jt * 64 + vrow) * rs + 2 * DD + h * NHD + kq * 8);
            u16x8 v0 = vb[0];
            u16x8 v1 = *(const u16x8*)((const bf16*)vb + rs);
            #pragma unroll
            for (int j = 0; j < 8; ++j) {
                int d = kq * 8 + j;
                int e = (d * 64 + vrow) ^ ((d & 7) << 3);
                *(unsigned int*)&Vt[e] = (unsigned int)v0[j] | ((unsigned int)v1[j] << 16);
            }
        }
        f32x4 s[4] = {};
        const bf16* kb = qkv + (size_t)(b * TT + jt * 64 + fr) * rs + DD + h * NHD;
        #pragma unroll
        for (int n = 0; n < 4; ++n) {
            bf16x8 k0 = *(const bf16x8*)(kb + (size_t)(n * 16) * rs + fq * 8);
            bf16x8 k1 = *(const bf16x8*)(kb + (size_t)(n * 16) * rs + 32 + fq * 8);
            s[n] = __builtin_amdgcn_mfma_f32_16x16x32_bf16(qf[0], k0, s[n], 0, 0, 0);
            s[n] = __builtin_amdgcn_mfma_f32_16x16x32_bf16(qf[1], k1, s[n], 0, 0, 0);
        }
        float mt[4] = {-1e30f, -1e30f, -1e30f, -1e30f};
        #pragma unroll
        for (int n = 0; n < 4; ++n) {
            int colg = jt * 64 + n * 16 + fr;
            #pragma unroll
            for (int r = 0; r < 4; ++r) {
                int rowg = q0 + wid * 16 + fq * 4 + r;
                float v = s[n][r] * 0.125f;
                if (colg > rowg) v = -1e30f;
                s[n][r] = v;
                mt[r] = fmaxf(mt[r], v);
            }
        }
        #pragma unroll
        for (int msk = 1; msk <= 8; msk <<= 1)
            #pragma unroll
            for (int r = 0; r < 4; ++r) mt[r] = fmaxf(mt[r], __shfl_xor(mt[r], msk));
        float sc[4], pt[4] = {0.f, 0.f, 0.f, 0.f};
        #pragma unroll
        for (int r = 0; r < 4; ++r) {
            float mn = fmaxf(mrun[r], mt[r]);
            sc[r] = __expf(mrun[r] - mn);
            mrun[r] = mn;
        }
        #pragma unroll
        for (int n = 0; n < 4; ++n)
            #pragma unroll
            for (int r = 0; r < 4; ++r) {
                float p = __expf(s[n][r] - mrun[r]);
                s[n][r] = p;
                pt[r] += p;
            }
        #pragma unroll
        for (int msk = 1; msk <= 8; msk <<= 1)
            #pragma unroll
            for (int r = 0; r < 4; ++r) pt[r] += __shfl_xor(pt[r], msk);
        #pragma unroll
        for (int r = 0; r < 4; ++r) lrun[r] = lrun[r] * sc[r] + pt[r];
        #pragma unroll
        for (int n2 = 0; n2 < 4; ++n2)
            #pragma unroll
            for (int r = 0; r < 4; ++r) o[n2][r] *= sc[r];
        #pragma unroll
        for (int n = 0; n < 4; ++n)
            #pragma unroll
            for (int r = 0; r < 4; ++r) {
                int row = fq * 4 + r;
                int e = (row * 64 + n * 16 + fr) ^ ((row & 7) << 3);
                Ps[wid][e] = __float2bfloat16(s[n][r]);
            }
        __syncthreads();
        #pragma unroll
        for (int ks = 0; ks < 2; ++ks) {
            int pe = (fr * 64 + ks * 32 + fq * 8) ^ ((fr & 7) << 3);
            bf16x8 pa = *(const bf16x8*)&Ps[wid][pe];
            #pragma unroll
            for (int n2 = 0; n2 < 4; ++n2) {
                int d = n2 * 16 + fr;
                int ve = (d * 64 + ks * 32 + fq * 8) ^ ((d & 7) << 3);
                bf16x8 vv = *(const bf16x8*)&Vt[ve];
                o[n2] = __builtin_amdgcn_mfma_f32_16x16x32_bf16(pa, vv, o[n2], 0, 0, 0);
            }
        }
    }
    #pragma unroll
    for (int r = 0; r < 4; ++r) {
        float inv = 1.f / lrun[r];
        bf16* op = out + (size_t)(b * TT + q0 + wid * 16 + fq * 4 + r) * DD + h * NHD;
        #pragma unroll
        for (int n2 = 0; n2 < 4; ++n2)
            op[n2 * 16 + fr] = __float2bfloat16(o[n2][r] * inv);
    }
}

// ---------------- loss: single-pass online softmax, float4 ----------------
__global__ void zero_kernel(float* p) { if (threadIdx.x == 0) p[0] = 0.f; }

__device__ __forceinline__ void ol_push(float v, float& mx, float& sm) {
    if (v > mx) { sm *= __expf(mx - v); mx = v; }
    sm += __expf(v - mx);
}

__global__ void loss_kernel(const float* __restrict__ logits, const int* __restrict__ targets,
                            float* __restrict__ acc) {
    __shared__ float rm[256], rs[256];
    int m = blockIdx.x;
    int tid = threadIdx.x;
    const float* lr = logits + (size_t)m * VV;
    // row base alignment: addr ≡ 4*m (mod 16) bytes -> lead scalars to 16B
    const int lead = (4 - (m & 3)) & 3;
    const int nv = (VV - lead) >> 2;                  // float4 count
    float mx = -1e30f, sm = 0.f;
    if (tid < lead) ol_push(lr[tid], mx, sm);
    const float4* lr4 = (const float4*)(lr + lead);
    for (int i = tid; i < nv; i += 256) {
        float4 v = lr4[i];
        ol_push(v.x, mx, sm); ol_push(v.y, mx, sm);
        ol_push(v.z, mx, sm); ol_push(v.w, mx, sm);
    }
    for (int i = lead + 4 * nv + tid; i < VV; i += 256) ol_push(lr[i], mx, sm);
    rm[tid] = mx; rs[tid] = sm;
    __syncthreads();
    for (int s = 128; s > 0; s >>= 1) {
        if (tid < s) {
            float m2 = rm[tid + s], s2 = rs[tid + s];
            float nm = fmaxf(rm[tid], m2);
            rs[tid] = rs[tid] * __expf(rm[tid] - nm) + s2 * __expf(m2 - nm);
            rm[tid] = nm;
        }
        __syncthreads();
    }
    if (tid == 0) {
        float lse = logf(rs[0]) + rm[0];
        atomicAdd(acc, lse - lr[targets[m]]);
    }
}

__global__ void loss_final(const float* __restrict__ acc, float* __restrict__ out) {
    if (threadIdx.x == 0) out[0] = acc[0] * (1.0f / (float)MROWS);
}

// ---------------- launch ----------------
extern "C" void kernel_launch(void* const* d_in, const int* in_sizes, int n_in,
                              void* d_out, int out_size, void* d_ws, size_t ws_size,
                              hipStream_t stream) {
    const int*   idx     = (const int*)d_in[0];
    const int*   targets = (const int*)d_in[1];
    const float* wte     = (const float*)d_in[2];
    const float* wpe     = (const float*)d_in[3];
    const float* ln1_w   = (const float*)d_in[4];
    const float* ln1_b   = (const float*)d_in[5];
    const float* qkv_w   = (const float*)d_in[6];
    const float* qkv_b   = (const float*)d_in[7];
    const float* proj_w  = (const float*)d_in[8];
    const float* proj_b  = (const float*)d_in[9];
    const float* ln2_w   = (const float*)d_in[10];
    const float* ln2_b   = (const float*)d_in[11];
    const float* fc_w    = (const float*)d_in[12];
    const float* fc_b    = (const float*)d_in[13];
    const float* fc2_w   = (const float*)d_in[14];
    const float* fc2_b   = (const float*)d_in[15];
    const float* lnf_w   = (const float*)d_in[16];
    const float* lnf_b   = (const float*)d_in[17];

    float* logits = (float*)d_out;
    float* loss_out = logits + (size_t)MROWS * VV;

    const size_t LQ = (size_t)3 * DD * DD, LP = (size_t)DD * DD;
    const size_t LF = (size_t)4 * DD * DD, LF2 = (size_t)4 * DD * DD;
    const size_t LSTRIDE = LQ + LP + LF + LF2;

    float* x    = (float*)d_ws;
    float* lacc = x + (size_t)MROWS * DD;
    bf16* qkvbuf = (bf16*)(lacc + 16);
    bf16* hb   = qkvbuf + (size_t)MROWS * 3 * DD;
    bf16* ab   = hb + (size_t)MROWS * DD;
    bf16* gb   = ab + (size_t)MROWS * DD;
    bf16* wteb = gb + (size_t)MROWS * 4 * DD;
    bf16* wbase = wteb + (size_t)VPAD * DD;

    const size_t fixed_bytes = (size_t)((char*)wbase - (char*)d_ws);
    const bool hoist = ws_size >= fixed_bytes + sizeof(bf16) * LSTRIDE * LL;

    dim3 blk(256);
    cast_kernel<<<2048, blk, 0, stream>>>(wte, wteb, VV * DD / 4);
    embed_kernel<<<MROWS, blk, 0, stream>>>(idx, wte, wpe, x);

    if (hoist) {
        tcast_kernel<<<dim3(3 * DD / 32, DD / 32, LL), blk, 0, stream>>>(
            qkv_w, wbase, DD, 3 * DD, LQ, LSTRIDE);
        tcast_kernel<<<dim3(DD / 32, DD / 32, LL), blk, 0, stream>>>(
            proj_w, wbase + LQ, DD, DD, LP, LSTRIDE);
        tcast_kernel<<<dim3(4 * DD / 32, DD / 32, LL), blk, 0, stream>>>(
            fc_w, wbase + LQ + LP, DD, 4 * DD, LF, LSTRIDE);
        tcast_kernel<<<dim3(DD / 32, 4 * DD / 32, LL), blk, 0, stream>>>(
            fc2_w, wbase + LQ + LP + LF, 4 * DD, DD, LF2, LSTRIDE);
    }

    for (int l = 0; l < LL; ++l) {
        bf16* wl = hoist ? wbase + (size_t)l * LSTRIDE : wbase;
        bf16* wQT = wl, *wPT = wl + LQ, *wFT = wl + LQ + LP, *wF2T = wl + LQ + LP + LF;
        if (!hoist) {
            tcast_kernel<<<dim3(3 * DD / 32, DD / 32, 1), blk, 0, stream>>>(qkv_w + (size_t)l * LQ, wQT, DD, 3 * DD, 0, 0);
            tcast_kernel<<<dim3(DD / 32, DD / 32, 1), blk, 0, stream>>>(proj_w + (size_t)l * LP, wPT, DD, DD, 0, 0);
            tcast_kernel<<<dim3(4 * DD / 32, DD / 32, 1), blk, 0, stream>>>(fc_w + (size_t)l * LF, wFT, DD, 4 * DD, 0, 0);
            tcast_kernel<<<dim3(DD / 32, 4 * DD / 32, 1), blk, 0, stream>>>(fc2_w + (size_t)l * LF2, wF2T, 4 * DD, DD, 0, 0);
        }

        ln_kernel<<<MROWS, blk, 0, stream>>>(x, ln1_w + (size_t)l * DD, ln1_b + (size_t)l * DD, hb);

        mgemm<128, 128, true, false, false, true, false><<<dim3(MROWS / 128, 3 * DD / 128), blk, 0, stream>>>(
            hb, wQT, qkv_b + (size_t)l * 3 * DD, nullptr, nullptr, qkvbuf, MROWS, 3 * DD, DD);

        attn3_kernel<<<BB * HH * (TT / 64), blk, 0, stream>>>(qkvbuf, ab);

        mgemm<64, 64, true, false, true, false, false><<<dim3(MROWS / 64, DD / 64), blk, 0, stream>>>(
            ab, wPT, proj_b + (size_t)l * DD, x, x, nullptr, MROWS, DD, DD);

        ln_kernel<<<MROWS, blk, 0, stream>>>(x, ln2_w + (size_t)l * DD, ln2_b + (size_t)l * DD, hb);

        mgemm<128, 128, true, true, false, true, false><<<dim3(MROWS / 128, 4 * DD / 128), blk, 0, stream>>>(
            hb, wFT, fc_b + (size_t)l * 4 * DD, nullptr, nullptr, gb, MROWS, 4 * DD, DD);

        mgemm<64, 64, true, false, true, false, false><<<dim3(MROWS / 64, DD / 64), blk, 0, stream>>>(
            gb, wF2T, fc2_b + (size_t)l * DD, x, x, nullptr, MROWS, DD, 4 * DD);
    }

    ln_kernel<<<MROWS, blk, 0, stream>>>(x, lnf_w, lnf_b, hb);

    mgemm<128, 128, false, false, false, false, true><<<dim3(MROWS / 128, VPAD / 128), blk, 0, stream>>>(
        hb, wteb, nullptr, nullptr, logits, nullptr, MROWS, VV, DD);

    zero_kernel<<<1, 64, 0, stream>>>(lacc);
    loss_kernel<<<MROWS, blk, 0, stream>>>(logits, targets, lacc);
    loss_final<<<1, 64, 0, stream>>>(lacc, loss_out);
}

// Round 6
// 2567.262 us; speedup vs baseline: 6.8016x; 1.0128x over previous
//
#include <hip/hip_runtime.h>
#include <hip/hip_bf16.h>
#include <math.h>

#define TT 1024
#define BB 2
#define DD 768
#define HH 12
#define NHD 64
#define LL 12
#define VV 50257
#define MROWS (BB*TT)
#define VPAD 50304

typedef __attribute__((ext_vector_type(4))) float f32x4;
typedef __attribute__((ext_vector_type(8))) __bf16 bf16x8;
typedef __attribute__((ext_vector_type(8))) unsigned short u16x8;
typedef __hip_bfloat16 bf16;

__device__ __forceinline__ void gload_lds16(const bf16* g, bf16* l) {
    __builtin_amdgcn_global_load_lds((const __attribute__((address_space(1))) void*)g,
                                     (__attribute__((address_space(3))) void*)l, 16, 0, 0);
}

// ---------------- embedding (fp32 residual stream) ----------------
__global__ void embed_kernel(const int* __restrict__ idx, const float* __restrict__ wte,
                             const float* __restrict__ wpe, float* __restrict__ x) {
    int m = blockIdx.x;
    int t = m % TT;
    int tok = idx[m];
    const float* wrow = wte + (size_t)tok * DD;
    const float* prow = wpe + (size_t)t * DD;
    float* xrow = x + (size_t)m * DD;
    for (int c = threadIdx.x; c < DD; c += blockDim.x)
        xrow[c] = wrow[c] + prow[c];
}

// ---------------- layernorm: fp32 in -> bf16 out ----------------
__global__ void ln_kernel(const float* __restrict__ x, const float* __restrict__ w,
                          const float* __restrict__ b, bf16* __restrict__ out) {
    __shared__ float red[256];
    int m = blockIdx.x;
    int tid = threadIdx.x;
    const float* xr = x + (size_t)m * DD;
    float v0 = xr[tid], v1 = xr[tid + 256], v2 = xr[tid + 512];
    red[tid] = v0 + v1 + v2;
    __syncthreads();
    for (int s = 128; s > 0; s >>= 1) { if (tid < s) red[tid] += red[tid + s]; __syncthreads(); }
    float mu = red[0] * (1.0f / DD);
    __syncthreads();
    float d0 = v0 - mu, d1 = v1 - mu, d2 = v2 - mu;
    red[tid] = d0 * d0 + d1 * d1 + d2 * d2;
    __syncthreads();
    for (int s = 128; s > 0; s >>= 1) { if (tid < s) red[tid] += red[tid + s]; __syncthreads(); }
    float rstd = rsqrtf(red[0] * (1.0f / DD) + 1e-5f);
    bf16* orow = out + (size_t)m * DD;
    orow[tid]       = __float2bfloat16(d0 * rstd * w[tid]       + b[tid]);
    orow[tid + 256] = __float2bfloat16(d1 * rstd * w[tid + 256] + b[tid + 256]);
    orow[tid + 512] = __float2bfloat16(d2 * rstd * w[tid + 512] + b[tid + 512]);
}

// ---------------- fp32 -> bf16 cast (wte) ----------------
__global__ void cast_kernel(const float* __restrict__ src, bf16* __restrict__ dst, int n4) {
    int stride = gridDim.x * blockDim.x;
    for (int i = blockIdx.x * blockDim.x + threadIdx.x; i < n4; i += stride) {
        float4 v = *(const float4*)(src + (size_t)i * 4);
        bf16* d = dst + (size_t)i * 4;
        d[0] = __float2bfloat16(v.x); d[1] = __float2bfloat16(v.y);
        d[2] = __float2bfloat16(v.z); d[3] = __float2bfloat16(v.w);
    }
}

// ---------------- batched W[K,N] fp32 -> Wt[N,K] bf16 (layer = blockIdx.z) ----
__global__ void tcast_kernel(const float* __restrict__ W, bf16* __restrict__ Wt,
                             int K, int N, size_t wstride, size_t tstride) {
    W  += (size_t)blockIdx.z * wstride;
    Wt += (size_t)blockIdx.z * tstride;
    __shared__ float t[32][33];
    int n0 = blockIdx.x * 32, k0 = blockIdx.y * 32;
    int c = threadIdx.x & 31, g = threadIdx.x >> 5;
    #pragma unroll
    for (int i = 0; i < 4; ++i) {
        int k = g * 4 + i;
        t[k][c] = W[(size_t)(k0 + k) * N + n0 + c];
    }
    __syncthreads();
    #pragma unroll
    for (int i = 0; i < 4; ++i) {
        int n = g * 4 + i;
        Wt[(size_t)(n0 + n) * K + k0 + c] = __float2bfloat16(t[c][n]);
    }
}

// ---------------- MFMA GEMM: C[M,N] = A[M,K] @ Wt[N,K]^T ----------------
// BK=32, 2-buffer LDS, depth-1 prefetch with counted vmcnt (R4-proven),
// 2-way LDS chunk swizzle (free), T1 XCD bijective swizzle, optional split-K=2.
template<int BM, int BN, bool BIAS, bool GELU_, bool RES, bool OUTBF16, bool NCHECK, bool SPLITK>
__global__ __launch_bounds__(256, 3) void mgemm(
        const bf16* __restrict__ A, const bf16* __restrict__ Bm,
        const float* __restrict__ bias, const float* __restrict__ res,
        float* __restrict__ Cf, bf16* __restrict__ Cb, int M, int N, int K) {
    constexpr int WM = BM / 32, WN = BN / 32;     // fragment repeats per wave
    constexpr int RA = BM / 64, RB = BN / 64;     // gload instrs per thread per operand
    constexpr int NL = RA + RB;                   // loads per tile per thread
    __shared__ __align__(16) bf16 As[2][BM * 32];
    __shared__ __align__(16) bf16 Bs[2][BN * 32];
    const int tid = threadIdx.x, lane = tid & 63, wid = tid >> 6;
    const int nbx = gridDim.x;
    const int nwg = nbx * gridDim.y;
    const int bidl = blockIdx.x + nbx * blockIdx.y;
    const int cpx = nwg >> 3;
    const int sw = (bidl & 7) * cpx + (bidl >> 3);
    const int m0 = (sw % nbx) * BM, n0 = (sw / nbx) * BN;
    const int wr = (wid >> 1) * (BM / 2), wc = (wid & 1) * (BN / 2);
    const int fr = lane & 15, fq = lane >> 4;

    const int Keff  = SPLITK ? (K >> 1) : K;
    const int kbase = SPLITK ? blockIdx.z * Keff : 0;
    if (SPLITK) Cf += (size_t)blockIdx.z * M * N;

    // staging: row = wid*16 + (lane>>2) (+i*64); global k-chunk pre-swizzled
    const int ksrc = ((lane & 3) ^ ((lane >> 3) & 3)) * 8;
    const bf16* gA = A  + (size_t)(m0 + wid * 16 + (lane >> 2)) * K + kbase + ksrc;
    const bf16* gB = Bm + (size_t)(n0 + wid * 16 + (lane >> 2)) * K + kbase + ksrc;
    bf16* lA = &As[0][0] + wid * 512 + lane * 8;
    bf16* lB = &Bs[0][0] + wid * 512 + lane * 8;
    const int kph = (fq ^ ((fr >> 1) & 3)) * 8;   // fragment phys chunk

    f32x4 acc[WM][WN] = {};
    const int nt = Keff / 32;

    #pragma unroll
    for (int i = 0; i < RA; ++i) gload_lds16(gA + (size_t)(i * 64) * K, lA + i * 2048);
    #pragma unroll
    for (int i = 0; i < RB; ++i) gload_lds16(gB + (size_t)(i * 64) * K, lB + i * 2048);

    for (int t = 0; t < nt; ++t) {
        const int cur = t & 1;
        if (t + 1 < nt) {   // prefetch next K-tile into other buffer
            const bf16* pA = gA + (t + 1) * 32;
            const bf16* pB = gB + (t + 1) * 32;
            bf16* dA = lA + (cur ^ 1) * (BM * 32);
            bf16* dB = lB + (cur ^ 1) * (BN * 32);
            #pragma unroll
            for (int i = 0; i < RA; ++i) gload_lds16(pA + (size_t)(i * 64) * K, dA + i * 2048);
            #pragma unroll
            for (int i = 0; i < RB; ++i) gload_lds16(pB + (size_t)(i * 64) * K, dB + i * 2048);
            asm volatile("s_waitcnt vmcnt(%0)" :: "i"(NL) : "memory");
        } else {
            asm volatile("s_waitcnt vmcnt(0)" ::: "memory");
        }
        __builtin_amdgcn_s_barrier();          // buf[cur] staged for all waves
        __builtin_amdgcn_sched_barrier(0);
        const bf16* abase = &As[cur][0];
        const bf16* bbase = &Bs[cur][0];
        bf16x8 af[WM], bq[WN];
        #pragma unroll
        for (int m = 0; m < WM; ++m)
            af[m] = *(const bf16x8*)(abase + (wr + m * 16 + fr) * 32 + kph);
        #pragma unroll
        for (int n = 0; n < WN; ++n)
            bq[n] = *(const bf16x8*)(bbase + (wc + n * 16 + fr) * 32 + kph);
        #pragma unroll
        for (int m = 0; m < WM; ++m)
            #pragma unroll
            for (int n = 0; n < WN; ++n)
                acc[m][n] = __builtin_amdgcn_mfma_f32_16x16x32_bf16(af[m], bq[n], acc[m][n], 0, 0, 0);
        __builtin_amdgcn_sched_barrier(0);
        __builtin_amdgcn_s_barrier();          // all waves done reading buf[cur]
    }

    #pragma unroll
    for (int m = 0; m < WM; ++m) {
        const int row = m0 + wr + m * 16 + fq * 4;
        #pragma unroll
        for (int n = 0; n < WN; ++n) {
            const int col = n0 + wc + n * 16 + fr;
            if (NCHECK && col >= N) continue;
            float bv = BIAS ? bias[col] : 0.f;
            #pragma unroll
            for (int r = 0; r < 4; ++r) {
                float v = acc[m][n][r] + bv;
                if (GELU_) {
                    float u = v;
                    v = 0.5f * u * (1.0f + tanhf(0.7978845608028654f * (u + 0.044715f * u * u * u)));
                }
                if (RES) v += res[(size_t)(row + r) * N + col];
                if (OUTBF16) Cb[(size_t)(row + r) * N + col] = __float2bfloat16(v);
                else         Cf[(size_t)(row + r) * N + col] = v;
            }
        }
    }
}

// ---------------- split-K reducer: x += part0 + part1 + bias ----------------
__global__ void red_kernel(const float* __restrict__ part, const float* __restrict__ bias,
                           float* __restrict__ x) {
    const size_t MN = (size_t)MROWS * DD;
    size_t i = ((size_t)blockIdx.x * blockDim.x + threadIdx.x) * 4;   // exact grid
    float4 p0 = *(const float4*)(part + i);
    float4 p1 = *(const float4*)(part + MN + i);
    float4 xv = *(const float4*)(x + i);
    float4 bv = *(const float4*)(bias + (int)(i % DD));
    xv.x += p0.x + p1.x + bv.x;
    xv.y += p0.y + p1.y + bv.y;
    xv.z += p0.z + p1.z + bv.z;
    xv.w += p0.w + p1.w + bv.w;
    *(float4*)(x + i) = xv;
}

// ---------------- MFMA flash attention: 64 q-rows/block, 4 waves x 16 rows ----
__global__ __launch_bounds__(256) void attn3_kernel(const bf16* __restrict__ qkv,
                                                    bf16* __restrict__ out) {
    __shared__ bf16 Vt[64 * 64];
    __shared__ bf16 Ps[4][16 * 64];
    const int bid = blockIdx.x;
    const int q0 = (15 - (bid & 15)) * 64;   // longest-first: big q0 starts earliest
    const int h  = (bid / (TT / 64)) % HH;
    const int b  = bid / ((TT / 64) * HH);
    const int tid = threadIdx.x, lane = tid & 63, wid = tid >> 6;
    const int fr = lane & 15, fq = lane >> 4;
    const size_t rs = 3 * DD;

    bf16x8 qf[2];
    {
        const bf16* qb = qkv + (size_t)(b * TT + q0 + wid * 16 + fr) * rs + h * NHD;
        qf[0] = *(const bf16x8*)(qb + fq * 8);
        qf[1] = *(const bf16x8*)(qb + 32 + fq * 8);
    }
    float mrun[4] = {-1e30f, -1e30f, -1e30f, -1e30f};
    float lrun[4] = {0.f, 0.f, 0.f, 0.f};
    f32x4 o[4] = {};
    const int vrow = (tid & 31) * 2, kq = tid >> 5;
    const int ntile = q0 / 64 + 1;

    for (int jt = 0; jt < ntile; ++jt) {
        __syncthreads();
        {
            const u16x8* vb = (const u16x8*)(qkv + (size_t)(b * TT + jt * 64 + vrow) * rs + 2 * DD + h * NHD + kq * 8);
            u16x8 v0 = vb[0];
            u16x8 v1 = *(const u16x8*)((const bf16*)vb + rs);
            #pragma unroll
            for (int j = 0; j < 8; ++j) {
                int d = kq * 8 + j;
                int e = (d * 64 + vrow) ^ ((d & 7) << 3);
                *(unsigned int*)&Vt[e] = (unsigned int)v0[j] | ((unsigned int)v1[j] << 16);
            }
        }
        f32x4 s[4] = {};
        const bf16* kb = qkv + (size_t)(b * TT + jt * 64 + fr) * rs + DD + h * NHD;
        __builtin_amdgcn_s_setprio(1);
        #pragma unroll
        for (int n = 0; n < 4; ++n) {
            bf16x8 k0 = *(const bf16x8*)(kb + (size_t)(n * 16) * rs + fq * 8);
            bf16x8 k1 = *(const bf16x8*)(kb + (size_t)(n * 16) * rs + 32 + fq * 8);
            s[n] = __builtin_amdgcn_mfma_f32_16x16x32_bf16(qf[0], k0, s[n], 0, 0, 0);
            s[n] = __builtin_amdgcn_mfma_f32_16x16x32_bf16(qf[1], k1, s[n], 0, 0, 0);
        }
        __builtin_amdgcn_s_setprio(0);
        float mt[4] = {-1e30f, -1e30f, -1e30f, -1e30f};
        #pragma unroll
        for (int n = 0; n < 4; ++n) {
            int colg = jt * 64 + n * 16 + fr;
            #pragma unroll
            for (int r = 0; r < 4; ++r) {
                int rowg = q0 + wid * 16 + fq * 4 + r;
                float v = s[n][r] * 0.125f;
                if (colg > rowg) v = -1e30f;
                s[n][r] = v;
                mt[r] = fmaxf(mt[r], v);
            }
        }
        #pragma unroll
        for (int msk = 1; msk <= 8; msk <<= 1)
            #pragma unroll
            for (int r = 0; r < 4; ++r) mt[r] = fmaxf(mt[r], __shfl_xor(mt[r], msk));
        float sc[4], pt[4] = {0.f, 0.f, 0.f, 0.f};
        #pragma unroll
        for (int r = 0; r < 4; ++r) {
            float mn = fmaxf(mrun[r], mt[r]);
            sc[r] = __expf(mrun[r] - mn);
            mrun[r] = mn;
        }
        #pragma unroll
        for (int n = 0; n < 4; ++n)
            #pragma unroll
            for (int r = 0; r < 4; ++r) {
                float p = __expf(s[n][r] - mrun[r]);
                s[n][r] = p;
                pt[r] += p;
            }
        #pragma unroll
        for (int msk = 1; msk <= 8; msk <<= 1)
            #pragma unroll
            for (int r = 0; r < 4; ++r) pt[r] += __shfl_xor(pt[r], msk);
        #pragma unroll
        for (int r = 0; r < 4; ++r) lrun[r] = lrun[r] * sc[r] + pt[r];
        #pragma unroll
        for (int n2 = 0; n2 < 4; ++n2)
            #pragma unroll
            for (int r = 0; r < 4; ++r) o[n2][r] *= sc[r];
        #pragma unroll
        for (int n = 0; n < 4; ++n)
            #pragma unroll
            for (int r = 0; r < 4; ++r) {
                int row = fq * 4 + r;
                int e = (row * 64 + n * 16 + fr) ^ ((row & 7) << 3);
                Ps[wid][e] = __float2bfloat16(s[n][r]);
            }
        __syncthreads();
        __builtin_amdgcn_s_setprio(1);
        #pragma unroll
        for (int ks = 0; ks < 2; ++ks) {
            int pe = (fr * 64 + ks * 32 + fq * 8) ^ ((fr & 7) << 3);
            bf16x8 pa = *(const bf16x8*)&Ps[wid][pe];
            #pragma unroll
            for (int n2 = 0; n2 < 4; ++n2) {
                int d = n2 * 16 + fr;
                int ve = (d * 64 + ks * 32 + fq * 8) ^ ((d & 7) << 3);
                bf16x8 vv = *(const bf16x8*)&Vt[ve];
                o[n2] = __builtin_amdgcn_mfma_f32_16x16x32_bf16(pa, vv, o[n2], 0, 0, 0);
            }
        }
        __builtin_amdgcn_s_setprio(0);
    }
    #pragma unroll
    for (int r = 0; r < 4; ++r) {
        float inv = 1.f / lrun[r];
        bf16* op = out + (size_t)(b * TT + q0 + wid * 16 + fq * 4 + r) * DD + h * NHD;
        #pragma unroll
        for (int n2 = 0; n2 < 4; ++n2)
            op[n2 * 16 + fr] = __float2bfloat16(o[n2][r] * inv);
    }
}

// ---------------- loss: single-pass online softmax, float4 ----------------
__global__ void zero_kernel(float* p) { if (threadIdx.x == 0) p[0] = 0.f; }

__device__ __forceinline__ void ol_push(float v, float& mx, float& sm) {
    if (v > mx) { sm *= __expf(mx - v); mx = v; }
    sm += __expf(v - mx);
}

__global__ void loss_kernel(const float* __restrict__ logits, const int* __restrict__ targets,
                            float* __restrict__ acc) {
    __shared__ float rm[256], rs[256];
    int m = blockIdx.x;
    int tid = threadIdx.x;
    const float* lr = logits + (size_t)m * VV;
    const int lead = (4 - (m & 3)) & 3;
    const int nv = (VV - lead) >> 2;
    float mx = -1e30f, sm = 0.f;
    if (tid < lead) ol_push(lr[tid], mx, sm);
    const float4* lr4 = (const float4*)(lr + lead);
    for (int i = tid; i < nv; i += 256) {
        float4 v = lr4[i];
        ol_push(v.x, mx, sm); ol_push(v.y, mx, sm);
        ol_push(v.z, mx, sm); ol_push(v.w, mx, sm);
    }
    for (int i = lead + 4 * nv + tid; i < VV; i += 256) ol_push(lr[i], mx, sm);
    rm[tid] = mx; rs[tid] = sm;
    __syncthreads();
    for (int s = 128; s > 0; s >>= 1) {
        if (tid < s) {
            float m2 = rm[tid + s], s2 = rs[tid + s];
            float nm = fmaxf(rm[tid], m2);
            rs[tid] = rs[tid] * __expf(rm[tid] - nm) + s2 * __expf(m2 - nm);
            rm[tid] = nm;
        }
        __syncthreads();
    }
    if (tid == 0) {
        float lse = logf(rs[0]) + rm[0];
        atomicAdd(acc, lse - lr[targets[m]]);
    }
}

__global__ void loss_final(const float* __restrict__ acc, float* __restrict__ out) {
    if (threadIdx.x == 0) out[0] = acc[0] * (1.0f / (float)MROWS);
}

// ---------------- launch ----------------
extern "C" void kernel_launch(void* const* d_in, const int* in_sizes, int n_in,
                              void* d_out, int out_size, void* d_ws, size_t ws_size,
                              hipStream_t stream) {
    const int*   idx     = (const int*)d_in[0];
    const int*   targets = (const int*)d_in[1];
    const float* wte     = (const float*)d_in[2];
    const float* wpe     = (const float*)d_in[3];
    const float* ln1_w   = (const float*)d_in[4];
    const float* ln1_b   = (const float*)d_in[5];
    const float* qkv_w   = (const float*)d_in[6];
    const float* qkv_b   = (const float*)d_in[7];
    const float* proj_w  = (const float*)d_in[8];
    const float* proj_b  = (const float*)d_in[9];
    const float* ln2_w   = (const float*)d_in[10];
    const float* ln2_b   = (const float*)d_in[11];
    const float* fc_w    = (const float*)d_in[12];
    const float* fc_b    = (const float*)d_in[13];
    const float* fc2_w   = (const float*)d_in[14];
    const float* fc2_b   = (const float*)d_in[15];
    const float* lnf_w   = (const float*)d_in[16];
    const float* lnf_b   = (const float*)d_in[17];

    float* logits = (float*)d_out;
    float* loss_out = logits + (size_t)MROWS * VV;

    const size_t LQ = (size_t)3 * DD * DD, LP = (size_t)DD * DD;
    const size_t LF = (size_t)4 * DD * DD, LF2 = (size_t)4 * DD * DD;
    const size_t LSTRIDE = LQ + LP + LF + LF2;

    float* x    = (float*)d_ws;
    float* lacc = x + (size_t)MROWS * DD;
    float* part = lacc + 16;                             // [2][MROWS*DD] fp32
    bf16* qkvbuf = (bf16*)(part + (size_t)2 * MROWS * DD);
    bf16* hb   = qkvbuf + (size_t)MROWS * 3 * DD;
    bf16* ab   = hb + (size_t)MROWS * DD;
    bf16* gb   = ab + (size_t)MROWS * DD;
    bf16* wteb = gb + (size_t)MROWS * 4 * DD;
    bf16* wbase = wteb + (size_t)VPAD * DD;

    const size_t fixed_bytes = (size_t)((char*)wbase - (char*)d_ws);
    const bool hoist = ws_size >= fixed_bytes + sizeof(bf16) * LSTRIDE * LL;

    dim3 blk(256);
    cast_kernel<<<2048, blk, 0, stream>>>(wte, wteb, VV * DD / 4);
    embed_kernel<<<MROWS, blk, 0, stream>>>(idx, wte, wpe, x);

    if (hoist) {
        tcast_kernel<<<dim3(3 * DD / 32, DD / 32, LL), blk, 0, stream>>>(
            qkv_w, wbase, DD, 3 * DD, LQ, LSTRIDE);
        tcast_kernel<<<dim3(DD / 32, DD / 32, LL), blk, 0, stream>>>(
            proj_w, wbase + LQ, DD, DD, LP, LSTRIDE);
        tcast_kernel<<<dim3(4 * DD / 32, DD / 32, LL), blk, 0, stream>>>(
            fc_w, wbase + LQ + LP, DD, 4 * DD, LF, LSTRIDE);
        tcast_kernel<<<dim3(DD / 32, 4 * DD / 32, LL), blk, 0, stream>>>(
            fc2_w, wbase + LQ + LP + LF, 4 * DD, DD, LF2, LSTRIDE);
    }

    const int nred = (MROWS * DD) / (4 * 256);   // exact

    for (int l = 0; l < LL; ++l) {
        bf16* wl = hoist ? wbase + (size_t)l * LSTRIDE : wbase;
        bf16* wQT = wl, *wPT = wl + LQ, *wFT = wl + LQ + LP, *wF2T = wl + LQ + LP + LF;
        if (!hoist) {
            tcast_kernel<<<dim3(3 * DD / 32, DD / 32, 1), blk, 0, stream>>>(qkv_w + (size_t)l * LQ, wQT, DD, 3 * DD, 0, 0);
            tcast_kernel<<<dim3(DD / 32, DD / 32, 1), blk, 0, stream>>>(proj_w + (size_t)l * LP, wPT, DD, DD, 0, 0);
            tcast_kernel<<<dim3(4 * DD / 32, DD / 32, 1), blk, 0, stream>>>(fc_w + (size_t)l * LF, wFT, DD, 4 * DD, 0, 0);
            tcast_kernel<<<dim3(DD / 32, 4 * DD / 32, 1), blk, 0, stream>>>(fc2_w + (size_t)l * LF2, wF2T, 4 * DD, DD, 0, 0);
        }

        ln_kernel<<<MROWS, blk, 0, stream>>>(x, ln1_w + (size_t)l * DD, ln1_b + (size_t)l * DD, hb);

        mgemm<128, 128, true, false, false, true, false, false><<<dim3(MROWS / 128, 3 * DD / 128), blk, 0, stream>>>(
            hb, wQT, qkv_b + (size_t)l * 3 * DD, nullptr, nullptr, qkvbuf, MROWS, 3 * DD, DD);

        attn3_kernel<<<BB * HH * (TT / 64), blk, 0, stream>>>(qkvbuf, ab);

        // proj: split-K=2 -> partials, then fused bias+residual reduce into x
        mgemm<64, 64, false, false, false, false, false, true><<<dim3(MROWS / 64, DD / 64, 2), blk, 0, stream>>>(
            ab, wPT, nullptr, nullptr, part, nullptr, MROWS, DD, DD);
        red_kernel<<<nred, blk, 0, stream>>>(part, proj_b + (size_t)l * DD, x);

        ln_kernel<<<MROWS, blk, 0, stream>>>(x, ln2_w + (size_t)l * DD, ln2_b + (size_t)l * DD, hb);

        mgemm<128, 128, true, true, false, true, false, false><<<dim3(MROWS / 128, 4 * DD / 128), blk, 0, stream>>>(
            hb, wFT, fc_b + (size_t)l * 4 * DD, nullptr, nullptr, gb, MROWS, 4 * DD, DD);

        // fc2: split-K=2 (K=3072 -> 1536 each)
        mgemm<64, 64, false, false, false, false, false, true><<<dim3(MROWS / 64, DD / 64, 2), blk, 0, stream>>>(
            gb, wF2T, nullptr, nullptr, part, nullptr, MROWS, DD, 4 * DD);
        red_kernel<<<nred, blk, 0, stream>>>(part, fc2_b + (size_t)l * DD, x);
    }

    ln_kernel<<<MROWS, blk, 0, stream>>>(x, lnf_w, lnf_b, hb);

    mgemm<128, 128, false, false, false, false, true, false><<<dim3(MROWS / 128, VPAD / 128), blk, 0, stream>>>(
        hb, wteb, nullptr, nullptr, logits, nullptr, MROWS, VV, DD);

    zero_kernel<<<1, 64, 0, stream>>>(lacc);
    loss_kernel<<<MROWS, blk, 0, stream>>>(logits, targets, lacc);
    loss_final<<<1, 64, 0, stream>>>(lacc, loss_out);
}